// Round 2
// baseline (1605.171 us; speedup 1.0000x reference)
//
#include <hip/hip_runtime.h>
#include <math.h>

#define DEV __device__ __forceinline__

DEV float frn_mul(float a, float b) { return __fmul_rn(a, b); }
DEV float frn_add(float a, float b) { return __fadd_rn(a, b); }

// ---------------------------------------------------------------------------
// query_ball: one wave (64 lanes) per query. Keeps the K smallest-index
// in-range points (scan ascending with ballot), pads remainder with first.
// Queries = first Vq rows per batch; points = all Vp rows (compact [B,Vp,3]).
// ---------------------------------------------------------------------------
__global__ void qb_kernel(const float* __restrict__ verts, int Vp, int Vq, int B,
                          float r2, int K, int* __restrict__ idx_out)
{
    int wid = (blockIdx.x * blockDim.x + threadIdx.x) >> 6;
    int lane = threadIdx.x & 63;
    int nq = B * Vq;
    if (wid >= nq) return;
    int b = wid / Vq;
    int v = wid - b * Vq;

    const float* q = verts + (size_t)(b * Vp + v) * 3;
    float qx = q[0], qy = q[1], qz = q[2];
    float qn = frn_add(frn_add(frn_mul(qx, qx), frn_mul(qy, qy)), frn_mul(qz, qz));
    const float* pts = verts + (size_t)b * Vp * 3;
    int* row = idx_out + (size_t)wid * K;

    int count = 0;
    int first = -1;
    for (int base = 0; base < Vp && count < K; base += 64) {
        int j = base + lane;
        bool in = false;
        if (j < Vp) {
            float px = pts[j * 3 + 0], py = pts[j * 3 + 1], pz = pts[j * 3 + 2];
            float pn = frn_add(frn_add(frn_mul(px, px), frn_mul(py, py)), frn_mul(pz, pz));
            float dt = frn_add(frn_add(frn_mul(qx, px), frn_mul(qy, py)), frn_mul(qz, pz));
            float d = __fsub_rn(frn_add(qn, pn), frn_mul(2.0f, dt));
            in = !(d > r2);
        }
        unsigned long long mask = __ballot(in);
        if (first < 0 && mask != 0ull)
            first = base + (int)__ffsll((long long)mask) - 1;
        int pos = count + (int)__popcll(mask & ((1ull << lane) - 1ull));
        if (in && pos < K) row[pos] = j;
        count += (int)__popcll(mask);
    }
    int cnt = count < K ? count : K;
    for (int t = cnt + lane; t < K; t += 64) row[t] = first;
}

// ---------------------------------------------------------------------------
// conv_surface: one wave per (b,v). o=32, S=4, K=32. Writes relu(out) to
// outF[row*Cw + 0..31].
// ---------------------------------------------------------------------------
__global__ void conv_surface_kernel(const int* __restrict__ idx,
                                    const float* __restrict__ verts,
                                    const float* __restrict__ dirs, // (3,128)
                                    float* __restrict__ outF, int Cw,
                                    int V, int B)
{
    int wid = (blockIdx.x * blockDim.x + threadIdx.x) >> 6;
    int lane = threadIdx.x & 63;
    int n = B * V;
    if (wid >= n) return;
    int b = wid / V;

    // neighbor direction for k = lane&31
    float dnx, dny, dnz;
    {
        int k = lane & 31;
        int nb = idx[(size_t)wid * 32 + k];
        int nbrow = b * V + nb;
        float cx = verts[(size_t)wid * 3 + 0];
        float cy = verts[(size_t)wid * 3 + 1];
        float cz = verts[(size_t)wid * 3 + 2];
        float dx = verts[(size_t)nbrow * 3 + 0] - cx;
        float dy = verts[(size_t)nbrow * 3 + 1] - cy;
        float dz = verts[(size_t)nbrow * 3 + 2] - cz;
        float nrm = sqrtf(dx * dx + dy * dy + dz * dz) + 1e-12f;
        float inv = 1.0f / nrm;
        dnx = dx * inv; dny = dy * inv; dnz = dz * inv;
    }
    // sd columns m1 = lane (s in {0,1}), m2 = lane+64 (s in {2,3}), oo = lane&31
    int m1 = lane, m2 = lane + 64;
    float ax = dirs[m1], ay = dirs[128 + m1], az = dirs[256 + m1];
    float i1 = 1.0f / (sqrtf(ax * ax + ay * ay + az * az) + 1e-12f);
    ax *= i1; ay *= i1; az *= i1;
    float bx = dirs[m2], by = dirs[128 + m2], bz = dirs[256 + m2];
    float i2 = 1.0f / (sqrtf(bx * bx + by * by + bz * bz) + 1e-12f);
    bx *= i2; by *= i2; bz *= i2;

    float mx1 = -INFINITY, mx2 = -INFINITY;
    for (int k = 0; k < 32; ++k) {
        float ex = __shfl(dnx, k, 64);
        float ey = __shfl(dny, k, 64);
        float ez = __shfl(dnz, k, 64);
        float t1 = fmaxf(ex * ax + ey * ay + ez * az, 0.0f);
        float t2 = fmaxf(ex * bx + ey * by + ez * bz, 0.0f);
        mx1 = fmaxf(mx1, t1);
        mx2 = fmaxf(mx2, t2);
    }
    float part = mx1 + mx2;
    float tot = part + __shfl_xor(part, 32, 64);
    if (lane < 32) {
        float val = fmaxf(tot, 0.0f); // relu (no-op: tot >= 0)
        outF[(size_t)wid * Cw + lane] = val;
    }
}

// ---------------------------------------------------------------------------
// GEMM: fout[M, n0:n0+NC] = feat[:, :cin] @ w[cin, n0:n0+NC] + bias.
// feat row stride Cw. ROWS rows per block staged in LDS. Column tile via
// blockIdx.y (NC cols per block) for occupancy on wide-N (conv11).
// ---------------------------------------------------------------------------
template <int ROWS>
__global__ void gemm_kernel(const float* __restrict__ feat, int Cw, int cin,
                            const float* __restrict__ w, const float* __restrict__ bias,
                            int N, int NC, float* __restrict__ fout)
{
    __shared__ float A[ROWS * 288]; // cin <= 288
    int m0 = blockIdx.x * ROWS;
    int n0 = blockIdx.y * NC;
    int nc = N - n0 < NC ? N - n0 : NC;
    for (int t = threadIdx.x; t < ROWS * cin; t += blockDim.x) {
        int r = t / cin, k = t - r * cin;
        A[r * cin + k] = feat[(size_t)(m0 + r) * Cw + k];
    }
    __syncthreads();
    int total = ROWS * nc;
    for (int t = threadIdx.x; t < total; t += blockDim.x) {
        int r = t / nc, nn = n0 + (t - r * nc);
        float acc = bias[nn];
        const float* Ar = A + r * cin;
        for (int k = 0; k < cin; ++k)
            acc += Ar[k] * w[(size_t)k * N + nn];
        fout[(size_t)(m0 + r) * N + nn] = acc;
    }
}

// ---------------------------------------------------------------------------
// conv_layer aggregation, cout=32 (S=4, K=32): one wave per (b,v).
// fout row = [center(32) | supp(128)], stride 160.
// out[oo] = center[oo] + sum_s max_k relu(dn.sd[s*32+oo]) * supp_nb[k,s*32+oo]
// ---------------------------------------------------------------------------
__global__ void conv_agg32_kernel(const int* __restrict__ idx,
                                  const float* __restrict__ verts,
                                  const float* __restrict__ fout,
                                  const float* __restrict__ dirs, // (3,128)
                                  float* __restrict__ outF, int Cw, int coff,
                                  int V, int B, int do_relu)
{
    int wid = (blockIdx.x * blockDim.x + threadIdx.x) >> 6;
    int lane = threadIdx.x & 63;
    int n = B * V;
    if (wid >= n) return;
    int b = wid / V;

    float dnx, dny, dnz;
    int nbrow;
    {
        int k = lane & 31;
        int nb = idx[(size_t)wid * 32 + k];
        nbrow = b * V + nb;
        float cx = verts[(size_t)wid * 3 + 0];
        float cy = verts[(size_t)wid * 3 + 1];
        float cz = verts[(size_t)wid * 3 + 2];
        float dx = verts[(size_t)nbrow * 3 + 0] - cx;
        float dy = verts[(size_t)nbrow * 3 + 1] - cy;
        float dz = verts[(size_t)nbrow * 3 + 2] - cz;
        float nrm = sqrtf(dx * dx + dy * dy + dz * dz) + 1e-12f;
        float inv = 1.0f / nrm;
        dnx = dx * inv; dny = dy * inv; dnz = dz * inv;
    }
    int m1 = lane, m2 = lane + 64;
    float ax = dirs[m1], ay = dirs[128 + m1], az = dirs[256 + m1];
    float i1 = 1.0f / (sqrtf(ax * ax + ay * ay + az * az) + 1e-12f);
    ax *= i1; ay *= i1; az *= i1;
    float bx = dirs[m2], by = dirs[128 + m2], bz = dirs[256 + m2];
    float i2 = 1.0f / (sqrtf(bx * bx + by * by + bz * bz) + 1e-12f);
    bx *= i2; by *= i2; bz *= i2;

    float mx1 = -INFINITY, mx2 = -INFINITY;
    for (int k = 0; k < 32; ++k) {
        float ex = __shfl(dnx, k, 64);
        float ey = __shfl(dny, k, 64);
        float ez = __shfl(dnz, k, 64);
        int nr = __shfl(nbrow, k, 64);
        const float* fr = fout + (size_t)nr * 160 + 32;
        float t1 = fmaxf(ex * ax + ey * ay + ez * az, 0.0f);
        float t2 = fmaxf(ex * bx + ey * by + ez * bz, 0.0f);
        mx1 = fmaxf(mx1, t1 * fr[m1]);
        mx2 = fmaxf(mx2, t2 * fr[m2]);
    }
    float part = mx1 + mx2; // s and s+2
    float tot = part + __shfl_xor(part, 32, 64);
    if (lane < 32) {
        float c = fout[(size_t)wid * 160 + lane];
        float val = c + tot;
        if (do_relu) val = fmaxf(val, 0.0f);
        outF[(size_t)wid * Cw + coff + lane] = val;
    }
}

// ---------------------------------------------------------------------------
// conv11 aggregation: cout=1024. One block (256 threads) per (b,v).
// fout row = [center(1024) | supp(4096)], stride 5120. dirs (3,4096).
// No relu, no concat. G[row*1024 + oo].
// ---------------------------------------------------------------------------
__global__ void conv_agg_big_kernel(const int* __restrict__ idx,
                                    const float* __restrict__ verts,
                                    const float* __restrict__ fout,
                                    const float* __restrict__ dirs,
                                    float* __restrict__ G,
                                    int V, int B)
{
    __shared__ float dnS[32][3];
    __shared__ int nbS[32];
    int row = blockIdx.x; // B*V
    int b = row / V;
    int tid = threadIdx.x;

    if (tid < 32) {
        int nb = idx[(size_t)row * 32 + tid];
        int nbrow = b * V + nb;
        float cx = verts[(size_t)row * 3 + 0];
        float cy = verts[(size_t)row * 3 + 1];
        float cz = verts[(size_t)row * 3 + 2];
        float dx = verts[(size_t)nbrow * 3 + 0] - cx;
        float dy = verts[(size_t)nbrow * 3 + 1] - cy;
        float dz = verts[(size_t)nbrow * 3 + 2] - cz;
        float nrm = sqrtf(dx * dx + dy * dy + dz * dz) + 1e-12f;
        float inv = 1.0f / nrm;
        dnS[tid][0] = dx * inv; dnS[tid][1] = dy * inv; dnS[tid][2] = dz * inv;
        nbS[tid] = nbrow;
    }
    __syncthreads();

    float sdx[16], sdy[16], sdz[16], mx[16];
    for (int p = 0; p < 16; ++p) {
        int pair = p * 256 + tid; // = s*1024 + oo
        float ax = dirs[pair], ay = dirs[4096 + pair], az = dirs[8192 + pair];
        float inv = 1.0f / (sqrtf(ax * ax + ay * ay + az * az) + 1e-12f);
        sdx[p] = ax * inv; sdy[p] = ay * inv; sdz[p] = az * inv;
        mx[p] = -INFINITY;
    }
    for (int k = 0; k < 32; ++k) {
        float ex = dnS[k][0], ey = dnS[k][1], ez = dnS[k][2];
        const float* fr = fout + (size_t)nbS[k] * 5120 + 1024;
        for (int p = 0; p < 16; ++p) {
            float th = fmaxf(ex * sdx[p] + ey * sdy[p] + ez * sdz[p], 0.0f);
            float s = fr[p * 256 + tid];
            mx[p] = fmaxf(mx[p], th * s);
        }
    }
    // pair = p*256+tid, p = s*4+q, oo = q*256+tid
    for (int q = 0; q < 4; ++q) {
        float val = ((mx[q] + mx[4 + q]) + mx[8 + q]) + mx[12 + q];
        int oo = q * 256 + tid;
        float c = fout[(size_t)row * 5120 + oo];
        G[(size_t)row * 1024 + oo] = c + val;
    }
}

// ---------------------------------------------------------------------------
// pool: Fout[rowq*CwOut + c] = max over 4 neighbors of Fin[:, c], c < C.
// ---------------------------------------------------------------------------
__global__ void pool_kernel(const int* __restrict__ idxp,
                            const float* __restrict__ Fin, int CwIn,
                            float* __restrict__ Fout, int CwOut,
                            int C, int Vp, int Vh, int B)
{
    int t = blockIdx.x * blockDim.x + threadIdx.x;
    int total = B * Vh * C;
    if (t >= total) return;
    int c = t % C;
    int rowq = t / C;
    int b = rowq / Vh;
    const int* ip = idxp + (size_t)rowq * 4;
    float m = -INFINITY;
    for (int k = 0; k < 4; ++k) {
        int nr = b * Vp + ip[k];
        m = fmaxf(m, Fin[(size_t)nr * CwIn + c]);
    }
    Fout[(size_t)rowq * CwOut + c] = m;
}

__global__ void verts_copy_kernel(const float* __restrict__ vin,
                                  float* __restrict__ vout,
                                  int Vp, int Vh, int B)
{
    int t = blockIdx.x * blockDim.x + threadIdx.x;
    int total = B * Vh * 3;
    if (t >= total) return;
    int d = t % 3;
    int rq = t / 3;
    int b = rq / Vh;
    int v = rq - b * Vh;
    vout[t] = vin[((size_t)b * Vp + v) * 3 + d];
}

// ---------------------------------------------------------------------------
// Head
// ---------------------------------------------------------------------------
__global__ void gmax_kernel(const float* __restrict__ G, float* __restrict__ gm,
                            int V, int B)
{
    int t = blockIdx.x * blockDim.x + threadIdx.x;
    if (t >= B * 1024) return;
    int b = t >> 10;
    int c = t & 1023;
    float m = -INFINITY;
    for (int v = 0; v < V; ++v)
        m = fmaxf(m, G[((size_t)b * V + v) * 1024 + c]);
    gm[t] = m;
}

__global__ void fc1_kernel(const float* __restrict__ g, const float* __restrict__ w,
                           const float* __restrict__ bias,
                           const float* __restrict__ bn_g, const float* __restrict__ bn_b,
                           const float* __restrict__ bn_m, const float* __restrict__ bn_v,
                           float* __restrict__ h, int B)
{
    int t = blockIdx.x * blockDim.x + threadIdx.x;
    if (t >= B * 256) return;
    int b = t >> 8;
    int j = t & 255;
    const float* gr = g + (size_t)b * 1024;
    float acc = 0.0f;
    for (int k = 0; k < 1024; ++k)
        acc += gr[k] * w[(size_t)k * 256 + j];
    acc += bias[j];
    acc = (acc - bn_m[j]) / sqrtf(bn_v[j] + 1e-5f) * bn_g[j] + bn_b[j];
    acc = fmaxf(acc, 0.0f);
    h[t] = acc;
}

__global__ void fc2_kernel(const float* __restrict__ h, const float* __restrict__ w,
                           const float* __restrict__ bias, float* __restrict__ out,
                           int B)
{
    int t = blockIdx.x * blockDim.x + threadIdx.x;
    if (t >= B * 40) return;
    int b = t / 40;
    int j = t - b * 40;
    const float* hr = h + (size_t)b * 256;
    float acc = 0.0f;
    for (int k = 0; k < 256; ++k)
        acc += hr[k] * w[(size_t)k * 40 + j];
    out[t] = acc + bias[j];
}

// ---------------------------------------------------------------------------
static inline int wblocks(int waves) { return (waves + 3) / 4; } // 4 waves/block
static inline int tblocks(int threads) { return (threads + 255) / 256; }

extern "C" void kernel_launch(void* const* d_in, const int* in_sizes, int n_in,
                              void* d_out, int out_size, void* d_ws, size_t ws_size,
                              hipStream_t stream)
{
    const int B = 4;
    const float* verts1 = (const float*)d_in[0];
    const float* surf_dirs = (const float*)d_in[1];
    const float* w1 = (const float*)d_in[2];
    const float* b1 = (const float*)d_in[3];
    const float* d1 = (const float*)d_in[4];
    const float* w3 = (const float*)d_in[5];
    const float* b3 = (const float*)d_in[6];
    const float* d3 = (const float*)d_in[7];
    const float* w4 = (const float*)d_in[8];
    const float* b4 = (const float*)d_in[9];
    const float* d4 = (const float*)d_in[10];
    const float* w6 = (const float*)d_in[11];
    const float* b6 = (const float*)d_in[12];
    const float* d6 = (const float*)d_in[13];
    const float* w7 = (const float*)d_in[14];
    const float* b7 = (const float*)d_in[15];
    const float* d7 = (const float*)d_in[16];
    const float* w8 = (const float*)d_in[17];
    const float* b8 = (const float*)d_in[18];
    const float* d8 = (const float*)d_in[19];
    const float* w9 = (const float*)d_in[20];
    const float* b9 = (const float*)d_in[21];
    const float* d9 = (const float*)d_in[22];
    const float* w10 = (const float*)d_in[23];
    const float* b10 = (const float*)d_in[24];
    const float* d10 = (const float*)d_in[25];
    const float* w11 = (const float*)d_in[26];
    const float* b11 = (const float*)d_in[27];
    const float* d11 = (const float*)d_in[28];
    const float* fc1_w = (const float*)d_in[29];
    const float* fc1_b = (const float*)d_in[30];
    const float* bn_g = (const float*)d_in[31];
    const float* bn_b = (const float*)d_in[32];
    const float* bn_m = (const float*)d_in[33];
    const float* bn_v = (const float*)d_in[34];
    const float* fc2_w = (const float*)d_in[35];
    const float* fc2_b = (const float*)d_in[36];
    (void)in_sizes; (void)n_in; (void)out_size; (void)ws_size;

    float* ws = (float*)d_ws;
    size_t off = 0;
    auto alloc = [&](size_t n) { float* p = ws + off; off += n; return p; };
    float* fout = alloc(4 * 256 * 5120);    // GEMM scratch (max = conv11)
    int* idx = (int*)alloc(4 * 4096 * 32);  // per-level conv idx
    int* idxp = (int*)alloc(4 * 2048 * 4);  // pool idx
    float* F1 = alloc(4 * 4096 * 64);
    float* L2 = alloc(4 * 2048 * 128);
    float* L3 = alloc(4 * 1024 * 192);
    float* L4 = alloc(4 * 512 * 256);
    float* L5 = alloc(4 * 256 * 288);
    float* G = alloc(4 * 256 * 1024);
    float* v2 = alloc(4 * 2048 * 3);
    float* v3 = alloc(4 * 1024 * 3);
    float* v4 = alloc(4 * 512 * 3);
    float* v5 = alloc(4 * 256 * 3);
    float* gm = alloc(4 * 1024);
    float* hh = alloc(4 * 256);

    // ---- Level 1 (V=4096, r=0.2) ----
    qb_kernel<<<wblocks(B * 4096), 256, 0, stream>>>(verts1, 4096, 4096, B, 0.04f, 32, idx);
    conv_surface_kernel<<<wblocks(B * 4096), 256, 0, stream>>>(idx, verts1, surf_dirs, F1, 64, 4096, B);
    gemm_kernel<8><<<dim3((B * 4096) / 8, 1), 256, 0, stream>>>(F1, 64, 32, w1, b1, 160, 160, fout);
    conv_agg32_kernel<<<wblocks(B * 4096), 256, 0, stream>>>(idx, verts1, fout, d1, F1, 64, 32, 4096, B, 1);
    qb_kernel<<<wblocks(B * 2048), 256, 0, stream>>>(verts1, 4096, 2048, B, 0.04f, 4, idxp);
    pool_kernel<<<tblocks(B * 2048 * 64), 256, 0, stream>>>(idxp, F1, 64, L2, 128, 64, 4096, 2048, B);
    verts_copy_kernel<<<tblocks(B * 2048 * 3), 256, 0, stream>>>(verts1, v2, 4096, 2048, B);

    // ---- Level 2 (V=2048, r=0.4) ----
    qb_kernel<<<wblocks(B * 2048), 256, 0, stream>>>(v2, 2048, 2048, B, 0.16f, 32, idx);
    gemm_kernel<8><<<dim3((B * 2048) / 8, 1), 256, 0, stream>>>(L2, 128, 64, w3, b3, 160, 160, fout);
    conv_agg32_kernel<<<wblocks(B * 2048), 256, 0, stream>>>(idx, v2, fout, d3, L2, 128, 64, 2048, B, 1);
    gemm_kernel<8><<<dim3((B * 2048) / 8, 1), 256, 0, stream>>>(L2, 128, 96, w4, b4, 160, 160, fout);
    conv_agg32_kernel<<<wblocks(B * 2048), 256, 0, stream>>>(idx, v2, fout, d4, L2, 128, 96, 2048, B, 1);
    qb_kernel<<<wblocks(B * 1024), 256, 0, stream>>>(v2, 2048, 1024, B, 0.16f, 4, idxp);
    pool_kernel<<<tblocks(B * 1024 * 128), 256, 0, stream>>>(idxp, L2, 128, L3, 192, 128, 2048, 1024, B);
    verts_copy_kernel<<<tblocks(B * 1024 * 3), 256, 0, stream>>>(v2, v3, 2048, 1024, B);

    // ---- Level 3 (V=1024, r=0.6) ----
    qb_kernel<<<wblocks(B * 1024), 256, 0, stream>>>(v3, 1024, 1024, B, 0.36f, 32, idx);
    gemm_kernel<8><<<dim3((B * 1024) / 8, 1), 256, 0, stream>>>(L3, 192, 128, w6, b6, 160, 160, fout);
    conv_agg32_kernel<<<wblocks(B * 1024), 256, 0, stream>>>(idx, v3, fout, d6, L3, 192, 128, 1024, B, 1);
    gemm_kernel<8><<<dim3((B * 1024) / 8, 1), 256, 0, stream>>>(L3, 192, 160, w7, b7, 160, 160, fout);
    conv_agg32_kernel<<<wblocks(B * 1024), 256, 0, stream>>>(idx, v3, fout, d7, L3, 192, 160, 1024, B, 1);
    qb_kernel<<<wblocks(B * 512), 256, 0, stream>>>(v3, 1024, 512, B, 0.36f, 4, idxp);
    pool_kernel<<<tblocks(B * 512 * 192), 256, 0, stream>>>(idxp, L3, 192, L4, 256, 192, 1024, 512, B);
    verts_copy_kernel<<<tblocks(B * 512 * 3), 256, 0, stream>>>(v3, v4, 1024, 512, B);

    // ---- Level 4 (V=512, r=0.8) ----
    qb_kernel<<<wblocks(B * 512), 256, 0, stream>>>(v4, 512, 512, B, 0.64f, 32, idx);
    gemm_kernel<8><<<dim3((B * 512) / 8, 1), 256, 0, stream>>>(L4, 256, 192, w8, b8, 160, 160, fout);
    conv_agg32_kernel<<<wblocks(B * 512), 256, 0, stream>>>(idx, v4, fout, d8, L4, 256, 192, 512, B, 1);
    gemm_kernel<8><<<dim3((B * 512) / 8, 1), 256, 0, stream>>>(L4, 256, 224, w9, b9, 160, 160, fout);
    conv_agg32_kernel<<<wblocks(B * 512), 256, 0, stream>>>(idx, v4, fout, d9, L4, 256, 224, 512, B, 1);
    qb_kernel<<<wblocks(B * 256), 256, 0, stream>>>(v4, 512, 256, B, 0.64f, 4, idxp);
    pool_kernel<<<tblocks(B * 256 * 256), 256, 0, stream>>>(idxp, L4, 256, L5, 288, 256, 512, 256, B);
    verts_copy_kernel<<<tblocks(B * 256 * 3), 256, 0, stream>>>(v4, v5, 512, 256, B);

    // ---- Level 5 (V=256, r=1.0) ----
    qb_kernel<<<wblocks(B * 256), 256, 0, stream>>>(v5, 256, 256, B, 1.0f, 32, idx);
    gemm_kernel<8><<<dim3((B * 256) / 8, 1), 256, 0, stream>>>(L5, 288, 256, w10, b10, 160, 160, fout);
    conv_agg32_kernel<<<wblocks(B * 256), 256, 0, stream>>>(idx, v5, fout, d10, L5, 288, 256, 256, B, 1);
    gemm_kernel<8><<<dim3((B * 256) / 8, 4), 256, 0, stream>>>(L5, 288, 288, w11, b11, 5120, 1280, fout);
    conv_agg_big_kernel<<<B * 256, 256, 0, stream>>>(idx, v5, fout, d11, G, 256, B);

    // ---- Head ----
    gmax_kernel<<<tblocks(B * 1024), 256, 0, stream>>>(G, gm, 256, B);
    fc1_kernel<<<tblocks(B * 256), 256, 0, stream>>>(gm, fc1_w, fc1_b, bn_g, bn_b, bn_m, bn_v, hh, B);
    fc2_kernel<<<tblocks(B * 40), 256, 0, stream>>>(hh, fc2_w, fc2_b, (float*)d_out, B);
}

// Round 3
// 572.724 us; speedup vs baseline: 2.8027x; 2.8027x over previous
//
#include <hip/hip_runtime.h>
#include <math.h>

#define DEV __device__ __forceinline__

DEV float frn_mul(float a, float b) { return __fmul_rn(a, b); }
DEV float frn_add(float a, float b) { return __fadd_rn(a, b); }

// ---------------------------------------------------------------------------
// query_ball: one wave (64 lanes) per query. Keeps the K smallest-index
// in-range points (scan ascending with ballot), pads remainder with first.
// Queries = first Vq rows per batch; points = all Vp rows (compact [B,Vp,3]).
// ---------------------------------------------------------------------------
__global__ void qb_kernel(const float* __restrict__ verts, int Vp, int Vq, int B,
                          float r2, int K, int* __restrict__ idx_out)
{
    int wid = (blockIdx.x * blockDim.x + threadIdx.x) >> 6;
    int lane = threadIdx.x & 63;
    int nq = B * Vq;
    if (wid >= nq) return;
    int b = wid / Vq;
    int v = wid - b * Vq;

    const float* q = verts + (size_t)(b * Vp + v) * 3;
    float qx = q[0], qy = q[1], qz = q[2];
    float qn = frn_add(frn_add(frn_mul(qx, qx), frn_mul(qy, qy)), frn_mul(qz, qz));
    const float* pts = verts + (size_t)b * Vp * 3;
    int* row = idx_out + (size_t)wid * K;

    int count = 0;
    int first = -1;
    for (int base = 0; base < Vp && count < K; base += 64) {
        int j = base + lane;
        bool in = false;
        if (j < Vp) {
            float px = pts[j * 3 + 0], py = pts[j * 3 + 1], pz = pts[j * 3 + 2];
            float pn = frn_add(frn_add(frn_mul(px, px), frn_mul(py, py)), frn_mul(pz, pz));
            float dt = frn_add(frn_add(frn_mul(qx, px), frn_mul(qy, py)), frn_mul(qz, pz));
            float d = __fsub_rn(frn_add(qn, pn), frn_mul(2.0f, dt));
            in = !(d > r2);
        }
        unsigned long long mask = __ballot(in);
        if (first < 0 && mask != 0ull)
            first = base + (int)__ffsll((long long)mask) - 1;
        int pos = count + (int)__popcll(mask & ((1ull << lane) - 1ull));
        if (in && pos < K) row[pos] = j;
        count += (int)__popcll(mask);
    }
    int cnt = count < K ? count : K;
    for (int t = cnt + lane; t < K; t += 64) row[t] = first;
}

// ---------------------------------------------------------------------------
// conv_surface: one wave per (b,v). o=32, S=4, K=32. Writes relu(out) to
// outF[row*Cw + 0..31].
// ---------------------------------------------------------------------------
__global__ void conv_surface_kernel(const int* __restrict__ idx,
                                    const float* __restrict__ verts,
                                    const float* __restrict__ dirs, // (3,128)
                                    float* __restrict__ outF, int Cw,
                                    int V, int B)
{
    int wid = (blockIdx.x * blockDim.x + threadIdx.x) >> 6;
    int lane = threadIdx.x & 63;
    int n = B * V;
    if (wid >= n) return;
    int b = wid / V;

    // neighbor direction for k = lane&31
    float dnx, dny, dnz;
    {
        int k = lane & 31;
        int nb = idx[(size_t)wid * 32 + k];
        int nbrow = b * V + nb;
        float cx = verts[(size_t)wid * 3 + 0];
        float cy = verts[(size_t)wid * 3 + 1];
        float cz = verts[(size_t)wid * 3 + 2];
        float dx = verts[(size_t)nbrow * 3 + 0] - cx;
        float dy = verts[(size_t)nbrow * 3 + 1] - cy;
        float dz = verts[(size_t)nbrow * 3 + 2] - cz;
        float nrm = sqrtf(dx * dx + dy * dy + dz * dz) + 1e-12f;
        float inv = 1.0f / nrm;
        dnx = dx * inv; dny = dy * inv; dnz = dz * inv;
    }
    // sd columns m1 = lane (s in {0,1}), m2 = lane+64 (s in {2,3}), oo = lane&31
    int m1 = lane, m2 = lane + 64;
    float ax = dirs[m1], ay = dirs[128 + m1], az = dirs[256 + m1];
    float i1 = 1.0f / (sqrtf(ax * ax + ay * ay + az * az) + 1e-12f);
    ax *= i1; ay *= i1; az *= i1;
    float bx = dirs[m2], by = dirs[128 + m2], bz = dirs[256 + m2];
    float i2 = 1.0f / (sqrtf(bx * bx + by * by + bz * bz) + 1e-12f);
    bx *= i2; by *= i2; bz *= i2;

    float mx1 = -INFINITY, mx2 = -INFINITY;
    for (int k = 0; k < 32; ++k) {
        float ex = __shfl(dnx, k, 64);
        float ey = __shfl(dny, k, 64);
        float ez = __shfl(dnz, k, 64);
        float t1 = fmaxf(ex * ax + ey * ay + ez * az, 0.0f);
        float t2 = fmaxf(ex * bx + ey * by + ez * bz, 0.0f);
        mx1 = fmaxf(mx1, t1);
        mx2 = fmaxf(mx2, t2);
    }
    float part = mx1 + mx2;
    float tot = part + __shfl_xor(part, 32, 64);
    if (lane < 32) {
        float val = fmaxf(tot, 0.0f); // relu (no-op: tot >= 0)
        outF[(size_t)wid * Cw + lane] = val;
    }
}

// ---------------------------------------------------------------------------
// Tiled GEMM: fout[M,N] = feat[:, :cin] @ w[cin,N] + bias.
// 64x64 tile / 256 threads, K-tile 32, 4x4 micro-tile per thread.
// feat row stride Cw (>= cin, multiple of 4). cin multiple of 32.
// M multiple of 64. N multiple of 4 (bounds-checked per 64-col tile).
// ---------------------------------------------------------------------------
__global__ __launch_bounds__(256)
void gemm_tiled_kernel(const float* __restrict__ feat, int Cw, int cin,
                       const float* __restrict__ w, const float* __restrict__ bias,
                       int N, float* __restrict__ fout)
{
    __shared__ float As[64][36]; // [m][k], pad to 36 for bank spread
    __shared__ float Bs[32][68]; // [k][n], pad to 68

    int m0 = blockIdx.x * 64;
    int n0 = blockIdx.y * 64;
    int tid = threadIdx.x;
    int tx = tid & 15, ty = tid >> 4;

    float acc[4][4];
#pragma unroll
    for (int i = 0; i < 4; ++i)
#pragma unroll
        for (int j = 0; j < 4; ++j) acc[i][j] = 0.0f;

    for (int k0 = 0; k0 < cin; k0 += 32) {
        // stage A tile: 64 rows x 8 float4
#pragma unroll
        for (int i = 0; i < 2; ++i) {
            int qq = tid + i * 256;      // 0..511
            int row = qq >> 3, c = qq & 7;
            float4 v = *(const float4*)&feat[(size_t)(m0 + row) * Cw + k0 + 4 * c];
            *(float4*)&As[row][4 * c] = v;
        }
        // stage B tile: 32 rows x 16 float4 (zero-fill out-of-range cols)
#pragma unroll
        for (int i = 0; i < 2; ++i) {
            int qq = tid + i * 256;
            int kr = qq >> 4, c = qq & 15;
            int n = n0 + 4 * c;
            float4 v = make_float4(0.0f, 0.0f, 0.0f, 0.0f);
            if (n < N) v = *(const float4*)&w[(size_t)(k0 + kr) * N + n];
            *(float4*)&Bs[kr][4 * c] = v;
        }
        __syncthreads();

#pragma unroll
        for (int kt = 0; kt < 32; kt += 4) {
            float4 av4[4], bv4[4];
#pragma unroll
            for (int i = 0; i < 4; ++i) av4[i] = *(const float4*)&As[ty * 4 + i][kt];
#pragma unroll
            for (int r = 0; r < 4; ++r) bv4[r] = *(const float4*)&Bs[kt + r][tx * 4];
            const float* a = (const float*)av4;
            const float* bb = (const float*)bv4;
#pragma unroll
            for (int i = 0; i < 4; ++i)
#pragma unroll
                for (int r = 0; r < 4; ++r)
#pragma unroll
                    for (int j = 0; j < 4; ++j)
                        acc[i][j] = fmaf(a[i * 4 + r], bb[r * 4 + j], acc[i][j]);
        }
        __syncthreads();
    }

    int n = n0 + tx * 4;
    if (n < N) {
        float b0 = bias[n + 0], b1 = bias[n + 1], b2 = bias[n + 2], b3 = bias[n + 3];
#pragma unroll
        for (int i = 0; i < 4; ++i) {
            int m = m0 + ty * 4 + i;
            float4 o;
            o.x = acc[i][0] + b0;
            o.y = acc[i][1] + b1;
            o.z = acc[i][2] + b2;
            o.w = acc[i][3] + b3;
            *(float4*)&fout[(size_t)m * N + n] = o;
        }
    }
}

// ---------------------------------------------------------------------------
// conv_layer aggregation, cout=32 (S=4, K=32): one wave per (b,v).
// fout row = [center(32) | supp(128)], stride 160.
// out[oo] = center[oo] + sum_s max_k relu(dn.sd[s*32+oo]) * supp_nb[k,s*32+oo]
// ---------------------------------------------------------------------------
__global__ void conv_agg32_kernel(const int* __restrict__ idx,
                                  const float* __restrict__ verts,
                                  const float* __restrict__ fout,
                                  const float* __restrict__ dirs, // (3,128)
                                  float* __restrict__ outF, int Cw, int coff,
                                  int V, int B, int do_relu)
{
    int wid = (blockIdx.x * blockDim.x + threadIdx.x) >> 6;
    int lane = threadIdx.x & 63;
    int n = B * V;
    if (wid >= n) return;
    int b = wid / V;

    float dnx, dny, dnz;
    int nbrow;
    {
        int k = lane & 31;
        int nb = idx[(size_t)wid * 32 + k];
        nbrow = b * V + nb;
        float cx = verts[(size_t)wid * 3 + 0];
        float cy = verts[(size_t)wid * 3 + 1];
        float cz = verts[(size_t)wid * 3 + 2];
        float dx = verts[(size_t)nbrow * 3 + 0] - cx;
        float dy = verts[(size_t)nbrow * 3 + 1] - cy;
        float dz = verts[(size_t)nbrow * 3 + 2] - cz;
        float nrm = sqrtf(dx * dx + dy * dy + dz * dz) + 1e-12f;
        float inv = 1.0f / nrm;
        dnx = dx * inv; dny = dy * inv; dnz = dz * inv;
    }
    int m1 = lane, m2 = lane + 64;
    float ax = dirs[m1], ay = dirs[128 + m1], az = dirs[256 + m1];
    float i1 = 1.0f / (sqrtf(ax * ax + ay * ay + az * az) + 1e-12f);
    ax *= i1; ay *= i1; az *= i1;
    float bx = dirs[m2], by = dirs[128 + m2], bz = dirs[256 + m2];
    float i2 = 1.0f / (sqrtf(bx * bx + by * by + bz * bz) + 1e-12f);
    bx *= i2; by *= i2; bz *= i2;

    float mx1 = -INFINITY, mx2 = -INFINITY;
    for (int k = 0; k < 32; ++k) {
        float ex = __shfl(dnx, k, 64);
        float ey = __shfl(dny, k, 64);
        float ez = __shfl(dnz, k, 64);
        int nr = __shfl(nbrow, k, 64);
        const float* fr = fout + (size_t)nr * 160 + 32;
        float t1 = fmaxf(ex * ax + ey * ay + ez * az, 0.0f);
        float t2 = fmaxf(ex * bx + ey * by + ez * bz, 0.0f);
        mx1 = fmaxf(mx1, t1 * fr[m1]);
        mx2 = fmaxf(mx2, t2 * fr[m2]);
    }
    float part = mx1 + mx2; // s and s+2
    float tot = part + __shfl_xor(part, 32, 64);
    if (lane < 32) {
        float c = fout[(size_t)wid * 160 + lane];
        float val = c + tot;
        if (do_relu) val = fmaxf(val, 0.0f);
        outF[(size_t)wid * Cw + coff + lane] = val;
    }
}

// ---------------------------------------------------------------------------
// conv11 aggregation: cout=1024. One block (256 threads) per (b,v).
// fout row = [center(1024) | supp(4096)], stride 5120. dirs (3,4096).
// No relu, no concat. G[row*1024 + oo].
// ---------------------------------------------------------------------------
__global__ void conv_agg_big_kernel(const int* __restrict__ idx,
                                    const float* __restrict__ verts,
                                    const float* __restrict__ fout,
                                    const float* __restrict__ dirs,
                                    float* __restrict__ G,
                                    int V, int B)
{
    __shared__ float dnS[32][3];
    __shared__ int nbS[32];
    int row = blockIdx.x; // B*V
    int b = row / V;
    int tid = threadIdx.x;

    if (tid < 32) {
        int nb = idx[(size_t)row * 32 + tid];
        int nbrow = b * V + nb;
        float cx = verts[(size_t)row * 3 + 0];
        float cy = verts[(size_t)row * 3 + 1];
        float cz = verts[(size_t)row * 3 + 2];
        float dx = verts[(size_t)nbrow * 3 + 0] - cx;
        float dy = verts[(size_t)nbrow * 3 + 1] - cy;
        float dz = verts[(size_t)nbrow * 3 + 2] - cz;
        float nrm = sqrtf(dx * dx + dy * dy + dz * dz) + 1e-12f;
        float inv = 1.0f / nrm;
        dnS[tid][0] = dx * inv; dnS[tid][1] = dy * inv; dnS[tid][2] = dz * inv;
        nbS[tid] = nbrow;
    }
    __syncthreads();

    float sdx[16], sdy[16], sdz[16], mx[16];
    for (int p = 0; p < 16; ++p) {
        int pair = p * 256 + tid; // = s*1024 + oo
        float ax = dirs[pair], ay = dirs[4096 + pair], az = dirs[8192 + pair];
        float inv = 1.0f / (sqrtf(ax * ax + ay * ay + az * az) + 1e-12f);
        sdx[p] = ax * inv; sdy[p] = ay * inv; sdz[p] = az * inv;
        mx[p] = -INFINITY;
    }
    for (int k = 0; k < 32; ++k) {
        float ex = dnS[k][0], ey = dnS[k][1], ez = dnS[k][2];
        const float* fr = fout + (size_t)nbS[k] * 5120 + 1024;
        for (int p = 0; p < 16; ++p) {
            float th = fmaxf(ex * sdx[p] + ey * sdy[p] + ez * sdz[p], 0.0f);
            float s = fr[p * 256 + tid];
            mx[p] = fmaxf(mx[p], th * s);
        }
    }
    // pair = p*256+tid, p = s*4+q, oo = q*256+tid
    for (int q = 0; q < 4; ++q) {
        float val = ((mx[q] + mx[4 + q]) + mx[8 + q]) + mx[12 + q];
        int oo = q * 256 + tid;
        float c = fout[(size_t)row * 5120 + oo];
        G[(size_t)row * 1024 + oo] = c + val;
    }
}

// ---------------------------------------------------------------------------
// pool: Fout[rowq*CwOut + c] = max over 4 neighbors of Fin[:, c], c < C.
// ---------------------------------------------------------------------------
__global__ void pool_kernel(const int* __restrict__ idxp,
                            const float* __restrict__ Fin, int CwIn,
                            float* __restrict__ Fout, int CwOut,
                            int C, int Vp, int Vh, int B)
{
    int t = blockIdx.x * blockDim.x + threadIdx.x;
    int total = B * Vh * C;
    if (t >= total) return;
    int c = t % C;
    int rowq = t / C;
    int b = rowq / Vh;
    const int* ip = idxp + (size_t)rowq * 4;
    float m = -INFINITY;
    for (int k = 0; k < 4; ++k) {
        int nr = b * Vp + ip[k];
        m = fmaxf(m, Fin[(size_t)nr * CwIn + c]);
    }
    Fout[(size_t)rowq * CwOut + c] = m;
}

__global__ void verts_copy_kernel(const float* __restrict__ vin,
                                  float* __restrict__ vout,
                                  int Vp, int Vh, int B)
{
    int t = blockIdx.x * blockDim.x + threadIdx.x;
    int total = B * Vh * 3;
    if (t >= total) return;
    int d = t % 3;
    int rq = t / 3;
    int b = rq / Vh;
    int v = rq - b * Vh;
    vout[t] = vin[((size_t)b * Vp + v) * 3 + d];
}

// ---------------------------------------------------------------------------
// Head
// ---------------------------------------------------------------------------
__global__ void gmax_kernel(const float* __restrict__ G, float* __restrict__ gm,
                            int V, int B)
{
    int t = blockIdx.x * blockDim.x + threadIdx.x;
    if (t >= B * 1024) return;
    int b = t >> 10;
    int c = t & 1023;
    float m = -INFINITY;
    for (int v = 0; v < V; ++v)
        m = fmaxf(m, G[((size_t)b * V + v) * 1024 + c]);
    gm[t] = m;
}

__global__ void fc1_kernel(const float* __restrict__ g, const float* __restrict__ w,
                           const float* __restrict__ bias,
                           const float* __restrict__ bn_g, const float* __restrict__ bn_b,
                           const float* __restrict__ bn_m, const float* __restrict__ bn_v,
                           float* __restrict__ h, int B)
{
    int t = blockIdx.x * blockDim.x + threadIdx.x;
    if (t >= B * 256) return;
    int b = t >> 8;
    int j = t & 255;
    const float* gr = g + (size_t)b * 1024;
    float acc = 0.0f;
    for (int k = 0; k < 1024; ++k)
        acc += gr[k] * w[(size_t)k * 256 + j];
    acc += bias[j];
    acc = (acc - bn_m[j]) / sqrtf(bn_v[j] + 1e-5f) * bn_g[j] + bn_b[j];
    acc = fmaxf(acc, 0.0f);
    h[t] = acc;
}

__global__ void fc2_kernel(const float* __restrict__ h, const float* __restrict__ w,
                           const float* __restrict__ bias, float* __restrict__ out,
                           int B)
{
    int t = blockIdx.x * blockDim.x + threadIdx.x;
    if (t >= B * 40) return;
    int b = t / 40;
    int j = t - b * 40;
    const float* hr = h + (size_t)b * 256;
    float acc = 0.0f;
    for (int k = 0; k < 256; ++k)
        acc += hr[k] * w[(size_t)k * 40 + j];
    out[t] = acc + bias[j];
}

// ---------------------------------------------------------------------------
static inline int wblocks(int waves) { return (waves + 3) / 4; } // 4 waves/block
static inline int tblocks(int threads) { return (threads + 255) / 256; }
static inline dim3 ggrid(int M, int N) { return dim3(M / 64, (N + 63) / 64); }

extern "C" void kernel_launch(void* const* d_in, const int* in_sizes, int n_in,
                              void* d_out, int out_size, void* d_ws, size_t ws_size,
                              hipStream_t stream)
{
    const int B = 4;
    const float* verts1 = (const float*)d_in[0];
    const float* surf_dirs = (const float*)d_in[1];
    const float* w1 = (const float*)d_in[2];
    const float* b1 = (const float*)d_in[3];
    const float* d1 = (const float*)d_in[4];
    const float* w3 = (const float*)d_in[5];
    const float* b3 = (const float*)d_in[6];
    const float* d3 = (const float*)d_in[7];
    const float* w4 = (const float*)d_in[8];
    const float* b4 = (const float*)d_in[9];
    const float* d4 = (const float*)d_in[10];
    const float* w6 = (const float*)d_in[11];
    const float* b6 = (const float*)d_in[12];
    const float* d6 = (const float*)d_in[13];
    const float* w7 = (const float*)d_in[14];
    const float* b7 = (const float*)d_in[15];
    const float* d7 = (const float*)d_in[16];
    const float* w8 = (const float*)d_in[17];
    const float* b8 = (const float*)d_in[18];
    const float* d8 = (const float*)d_in[19];
    const float* w9 = (const float*)d_in[20];
    const float* b9 = (const float*)d_in[21];
    const float* d9 = (const float*)d_in[22];
    const float* w10 = (const float*)d_in[23];
    const float* b10 = (const float*)d_in[24];
    const float* d10 = (const float*)d_in[25];
    const float* w11 = (const float*)d_in[26];
    const float* b11 = (const float*)d_in[27];
    const float* d11 = (const float*)d_in[28];
    const float* fc1_w = (const float*)d_in[29];
    const float* fc1_b = (const float*)d_in[30];
    const float* bn_g = (const float*)d_in[31];
    const float* bn_b = (const float*)d_in[32];
    const float* bn_m = (const float*)d_in[33];
    const float* bn_v = (const float*)d_in[34];
    const float* fc2_w = (const float*)d_in[35];
    const float* fc2_b = (const float*)d_in[36];
    (void)in_sizes; (void)n_in; (void)out_size; (void)ws_size;

    float* ws = (float*)d_ws;
    size_t off = 0;
    auto alloc = [&](size_t n) { float* p = ws + off; off += n; return p; };
    float* fout = alloc(4 * 256 * 5120);    // GEMM scratch (max = conv11)
    int* idx = (int*)alloc(4 * 4096 * 32);  // per-level conv idx
    int* idxp = (int*)alloc(4 * 2048 * 4);  // pool idx
    float* F1 = alloc(4 * 4096 * 64);
    float* L2 = alloc(4 * 2048 * 128);
    float* L3 = alloc(4 * 1024 * 192);
    float* L4 = alloc(4 * 512 * 256);
    float* L5 = alloc(4 * 256 * 288);
    float* G = alloc(4 * 256 * 1024);
    float* v2 = alloc(4 * 2048 * 3);
    float* v3 = alloc(4 * 1024 * 3);
    float* v4 = alloc(4 * 512 * 3);
    float* v5 = alloc(4 * 256 * 3);
    float* gm = alloc(4 * 1024);
    float* hh = alloc(4 * 256);

    // ---- Level 1 (V=4096, r=0.2) ----
    qb_kernel<<<wblocks(B * 4096), 256, 0, stream>>>(verts1, 4096, 4096, B, 0.04f, 32, idx);
    conv_surface_kernel<<<wblocks(B * 4096), 256, 0, stream>>>(idx, verts1, surf_dirs, F1, 64, 4096, B);
    gemm_tiled_kernel<<<ggrid(B * 4096, 160), 256, 0, stream>>>(F1, 64, 32, w1, b1, 160, fout);
    conv_agg32_kernel<<<wblocks(B * 4096), 256, 0, stream>>>(idx, verts1, fout, d1, F1, 64, 32, 4096, B, 1);
    qb_kernel<<<wblocks(B * 2048), 256, 0, stream>>>(verts1, 4096, 2048, B, 0.04f, 4, idxp);
    pool_kernel<<<tblocks(B * 2048 * 64), 256, 0, stream>>>(idxp, F1, 64, L2, 128, 64, 4096, 2048, B);
    verts_copy_kernel<<<tblocks(B * 2048 * 3), 256, 0, stream>>>(verts1, v2, 4096, 2048, B);

    // ---- Level 2 (V=2048, r=0.4) ----
    qb_kernel<<<wblocks(B * 2048), 256, 0, stream>>>(v2, 2048, 2048, B, 0.16f, 32, idx);
    gemm_tiled_kernel<<<ggrid(B * 2048, 160), 256, 0, stream>>>(L2, 128, 64, w3, b3, 160, fout);
    conv_agg32_kernel<<<wblocks(B * 2048), 256, 0, stream>>>(idx, v2, fout, d3, L2, 128, 64, 2048, B, 1);
    gemm_tiled_kernel<<<ggrid(B * 2048, 160), 256, 0, stream>>>(L2, 128, 96, w4, b4, 160, fout);
    conv_agg32_kernel<<<wblocks(B * 2048), 256, 0, stream>>>(idx, v2, fout, d4, L2, 128, 96, 2048, B, 1);
    qb_kernel<<<wblocks(B * 1024), 256, 0, stream>>>(v2, 2048, 1024, B, 0.16f, 4, idxp);
    pool_kernel<<<tblocks(B * 1024 * 128), 256, 0, stream>>>(idxp, L2, 128, L3, 192, 128, 2048, 1024, B);
    verts_copy_kernel<<<tblocks(B * 1024 * 3), 256, 0, stream>>>(v2, v3, 2048, 1024, B);

    // ---- Level 3 (V=1024, r=0.6) ----
    qb_kernel<<<wblocks(B * 1024), 256, 0, stream>>>(v3, 1024, 1024, B, 0.36f, 32, idx);
    gemm_tiled_kernel<<<ggrid(B * 1024, 160), 256, 0, stream>>>(L3, 192, 128, w6, b6, 160, fout);
    conv_agg32_kernel<<<wblocks(B * 1024), 256, 0, stream>>>(idx, v3, fout, d6, L3, 192, 128, 1024, B, 1);
    gemm_tiled_kernel<<<ggrid(B * 1024, 160), 256, 0, stream>>>(L3, 192, 160, w7, b7, 160, fout);
    conv_agg32_kernel<<<wblocks(B * 1024), 256, 0, stream>>>(idx, v3, fout, d7, L3, 192, 160, 1024, B, 1);
    qb_kernel<<<wblocks(B * 512), 256, 0, stream>>>(v3, 1024, 512, B, 0.36f, 4, idxp);
    pool_kernel<<<tblocks(B * 512 * 192), 256, 0, stream>>>(idxp, L3, 192, L4, 256, 192, 1024, 512, B);
    verts_copy_kernel<<<tblocks(B * 512 * 3), 256, 0, stream>>>(v3, v4, 1024, 512, B);

    // ---- Level 4 (V=512, r=0.8) ----
    qb_kernel<<<wblocks(B * 512), 256, 0, stream>>>(v4, 512, 512, B, 0.64f, 32, idx);
    gemm_tiled_kernel<<<ggrid(B * 512, 160), 256, 0, stream>>>(L4, 256, 192, w8, b8, 160, fout);
    conv_agg32_kernel<<<wblocks(B * 512), 256, 0, stream>>>(idx, v4, fout, d8, L4, 256, 192, 512, B, 1);
    gemm_tiled_kernel<<<ggrid(B * 512, 160), 256, 0, stream>>>(L4, 256, 224, w9, b9, 160, fout);
    conv_agg32_kernel<<<wblocks(B * 512), 256, 0, stream>>>(idx, v4, fout, d9, L4, 256, 224, 512, B, 1);
    qb_kernel<<<wblocks(B * 256), 256, 0, stream>>>(v4, 512, 256, B, 0.64f, 4, idxp);
    pool_kernel<<<tblocks(B * 256 * 256), 256, 0, stream>>>(idxp, L4, 256, L5, 288, 256, 512, 256, B);
    verts_copy_kernel<<<tblocks(B * 256 * 3), 256, 0, stream>>>(v4, v5, 512, 256, B);

    // ---- Level 5 (V=256, r=1.0) ----
    qb_kernel<<<wblocks(B * 256), 256, 0, stream>>>(v5, 256, 256, B, 1.0f, 32, idx);
    gemm_tiled_kernel<<<ggrid(B * 256, 160), 256, 0, stream>>>(L5, 288, 256, w10, b10, 160, fout);
    conv_agg32_kernel<<<wblocks(B * 256), 256, 0, stream>>>(idx, v5, fout, d10, L5, 288, 256, 256, B, 1);
    gemm_tiled_kernel<<<ggrid(B * 256, 5120), 256, 0, stream>>>(L5, 288, 288, w11, b11, 5120, fout);
    conv_agg_big_kernel<<<B * 256, 256, 0, stream>>>(idx, v5, fout, d11, G, 256, B);

    // ---- Head ----
    gmax_kernel<<<tblocks(B * 1024), 256, 0, stream>>>(G, gm, 256, B);
    fc1_kernel<<<tblocks(B * 256), 256, 0, stream>>>(gm, fc1_w, fc1_b, bn_g, bn_b, bn_m, bn_v, hh, B);
    fc2_kernel<<<tblocks(B * 40), 256, 0, stream>>>(hh, fc2_w, fc2_b, (float*)d_out, B);
}

// Round 4
// 553.749 us; speedup vs baseline: 2.8987x; 1.0343x over previous
//
#include <hip/hip_runtime.h>
#include <hip/hip_bf16.h>
#include <math.h>

#define DEV __device__ __forceinline__

DEV float frn_mul(float a, float b) { return __fmul_rn(a, b); }
DEV float frn_add(float a, float b) { return __fadd_rn(a, b); }

union BFU { __hip_bfloat16 h; unsigned short u; };

// ---------------------------------------------------------------------------
// query_ball: one wave (64 lanes) per query. Keeps the K smallest-index
// in-range points (scan ascending with ballot), pads remainder with first.
// ---------------------------------------------------------------------------
__global__ void qb_kernel(const float* __restrict__ verts, int Vp, int Vq, int B,
                          float r2, int K, int* __restrict__ idx_out)
{
    int wid = (blockIdx.x * blockDim.x + threadIdx.x) >> 6;
    int lane = threadIdx.x & 63;
    int nq = B * Vq;
    if (wid >= nq) return;
    int b = wid / Vq;
    int v = wid - b * Vq;

    const float* q = verts + (size_t)(b * Vp + v) * 3;
    float qx = q[0], qy = q[1], qz = q[2];
    float qn = frn_add(frn_add(frn_mul(qx, qx), frn_mul(qy, qy)), frn_mul(qz, qz));
    const float* pts = verts + (size_t)b * Vp * 3;
    int* row = idx_out + (size_t)wid * K;

    int count = 0;
    int first = -1;
    for (int base = 0; base < Vp && count < K; base += 64) {
        int j = base + lane;
        bool in = false;
        if (j < Vp) {
            float px = pts[j * 3 + 0], py = pts[j * 3 + 1], pz = pts[j * 3 + 2];
            float pn = frn_add(frn_add(frn_mul(px, px), frn_mul(py, py)), frn_mul(pz, pz));
            float dt = frn_add(frn_add(frn_mul(qx, px), frn_mul(qy, py)), frn_mul(qz, pz));
            float d = __fsub_rn(frn_add(qn, pn), frn_mul(2.0f, dt));
            in = !(d > r2);
        }
        unsigned long long mask = __ballot(in);
        if (first < 0 && mask != 0ull)
            first = base + (int)__ffsll((long long)mask) - 1;
        int pos = count + (int)__popcll(mask & ((1ull << lane) - 1ull));
        if (in && pos < K) row[pos] = j;
        count += (int)__popcll(mask);
    }
    int cnt = count < K ? count : K;
    for (int t = cnt + lane; t < K; t += 64) row[t] = first;
}

// ---------------------------------------------------------------------------
// conv_surface: one wave per (b,v). o=32, S=4, K=32.
// ---------------------------------------------------------------------------
__global__ void conv_surface_kernel(const int* __restrict__ idx,
                                    const float* __restrict__ verts,
                                    const float* __restrict__ dirs, // (3,128)
                                    float* __restrict__ outF, int Cw,
                                    int V, int B)
{
    int wid = (blockIdx.x * blockDim.x + threadIdx.x) >> 6;
    int lane = threadIdx.x & 63;
    int n = B * V;
    if (wid >= n) return;
    int b = wid / V;

    float dnx, dny, dnz;
    {
        int k = lane & 31;
        int nb = idx[(size_t)wid * 32 + k];
        int nbrow = b * V + nb;
        float cx = verts[(size_t)wid * 3 + 0];
        float cy = verts[(size_t)wid * 3 + 1];
        float cz = verts[(size_t)wid * 3 + 2];
        float dx = verts[(size_t)nbrow * 3 + 0] - cx;
        float dy = verts[(size_t)nbrow * 3 + 1] - cy;
        float dz = verts[(size_t)nbrow * 3 + 2] - cz;
        float nrm = sqrtf(dx * dx + dy * dy + dz * dz) + 1e-12f;
        float inv = 1.0f / nrm;
        dnx = dx * inv; dny = dy * inv; dnz = dz * inv;
    }
    int m1 = lane, m2 = lane + 64;
    float ax = dirs[m1], ay = dirs[128 + m1], az = dirs[256 + m1];
    float i1 = 1.0f / (sqrtf(ax * ax + ay * ay + az * az) + 1e-12f);
    ax *= i1; ay *= i1; az *= i1;
    float bx = dirs[m2], by = dirs[128 + m2], bz = dirs[256 + m2];
    float i2 = 1.0f / (sqrtf(bx * bx + by * by + bz * bz) + 1e-12f);
    bx *= i2; by *= i2; bz *= i2;

    float mx1 = -INFINITY, mx2 = -INFINITY;
    for (int k = 0; k < 32; ++k) {
        float ex = __shfl(dnx, k, 64);
        float ey = __shfl(dny, k, 64);
        float ez = __shfl(dnz, k, 64);
        float t1 = fmaxf(ex * ax + ey * ay + ez * az, 0.0f);
        float t2 = fmaxf(ex * bx + ey * by + ez * bz, 0.0f);
        mx1 = fmaxf(mx1, t1);
        mx2 = fmaxf(mx2, t2);
    }
    float part = mx1 + mx2;
    float tot = part + __shfl_xor(part, 32, 64);
    if (lane < 32) {
        outF[(size_t)wid * Cw + lane] = fmaxf(tot, 0.0f);
    }
}

// ---------------------------------------------------------------------------
// Tiled GEMM: fout[M,N] = feat[:, :cin] @ w[cin,N] + bias.
// 64x64 tile / 256 threads, K-tile 32, 4x4 micro-tile. OT = float or bf16.
// ---------------------------------------------------------------------------
template <typename OT>
__global__ __launch_bounds__(256)
void gemm_tiled_kernel(const float* __restrict__ feat, int Cw, int cin,
                       const float* __restrict__ w, const float* __restrict__ bias,
                       int N, OT* __restrict__ fout)
{
    __shared__ float As[64][36];
    __shared__ float Bs[32][68];

    int m0 = blockIdx.x * 64;
    int n0 = blockIdx.y * 64;
    int tid = threadIdx.x;
    int tx = tid & 15, ty = tid >> 4;

    float acc[4][4];
#pragma unroll
    for (int i = 0; i < 4; ++i)
#pragma unroll
        for (int j = 0; j < 4; ++j) acc[i][j] = 0.0f;

    for (int k0 = 0; k0 < cin; k0 += 32) {
#pragma unroll
        for (int i = 0; i < 2; ++i) {
            int qq = tid + i * 256;
            int row = qq >> 3, c = qq & 7;
            float4 v = *(const float4*)&feat[(size_t)(m0 + row) * Cw + k0 + 4 * c];
            *(float4*)&As[row][4 * c] = v;
        }
#pragma unroll
        for (int i = 0; i < 2; ++i) {
            int qq = tid + i * 256;
            int kr = qq >> 4, c = qq & 15;
            int n = n0 + 4 * c;
            float4 v = make_float4(0.0f, 0.0f, 0.0f, 0.0f);
            if (n < N) v = *(const float4*)&w[(size_t)(k0 + kr) * N + n];
            *(float4*)&Bs[kr][4 * c] = v;
        }
        __syncthreads();

#pragma unroll
        for (int kt = 0; kt < 32; kt += 4) {
            float4 av4[4], bv4[4];
#pragma unroll
            for (int i = 0; i < 4; ++i) av4[i] = *(const float4*)&As[ty * 4 + i][kt];
#pragma unroll
            for (int r = 0; r < 4; ++r) bv4[r] = *(const float4*)&Bs[kt + r][tx * 4];
            const float* a = (const float*)av4;
            const float* bb = (const float*)bv4;
#pragma unroll
            for (int i = 0; i < 4; ++i)
#pragma unroll
                for (int r = 0; r < 4; ++r)
#pragma unroll
                    for (int j = 0; j < 4; ++j)
                        acc[i][j] = fmaf(a[i * 4 + r], bb[r * 4 + j], acc[i][j]);
        }
        __syncthreads();
    }

    int n = n0 + tx * 4;
    if (n < N) {
        float b0 = bias[n + 0], b1 = bias[n + 1], b2 = bias[n + 2], b3 = bias[n + 3];
#pragma unroll
        for (int i = 0; i < 4; ++i) {
            int m = m0 + ty * 4 + i;
            if constexpr (__is_same(OT, float)) {
                float4 o;
                o.x = acc[i][0] + b0;
                o.y = acc[i][1] + b1;
                o.z = acc[i][2] + b2;
                o.w = acc[i][3] + b3;
                *(float4*)&fout[(size_t)m * N + n] = o;
            } else {
                BFU t0, t1, t2, t3;
                t0.h = __float2bfloat16(acc[i][0] + b0);
                t1.h = __float2bfloat16(acc[i][1] + b1);
                t2.h = __float2bfloat16(acc[i][2] + b2);
                t3.h = __float2bfloat16(acc[i][3] + b3);
                ushort4 o;
                o.x = t0.u; o.y = t1.u; o.z = t2.u; o.w = t3.u;
                *(ushort4*)&fout[(size_t)m * N + n] = o;
            }
        }
    }
}

// ---------------------------------------------------------------------------
// conv_layer aggregation, cout=32. One wave per (b,v), XCD-swizzled:
// batch b's blocks pinned to XCDs {2b,2b+1} so fout slice is L2-resident.
// Grid must be exactly B*V/4 blocks of 256 threads.
// ---------------------------------------------------------------------------
__global__ void conv_agg32_kernel(const int* __restrict__ idx,
                                  const float* __restrict__ verts,
                                  const float* __restrict__ fout,
                                  const float* __restrict__ dirs, // (3,128)
                                  float* __restrict__ outF, int Cw, int coff,
                                  int V, int do_relu)
{
    int blk = blockIdx.x;
    int b = (blk & 7) >> 1;
    int j = ((blk >> 3) << 1) | (blk & 1);
    int wid = b * V + j * 4 + (int)(threadIdx.x >> 6);
    int lane = threadIdx.x & 63;

    float dnx, dny, dnz;
    int nbrow;
    {
        int k = lane & 31;
        int nb = idx[(size_t)wid * 32 + k];
        nbrow = b * V + nb;
        float cx = verts[(size_t)wid * 3 + 0];
        float cy = verts[(size_t)wid * 3 + 1];
        float cz = verts[(size_t)wid * 3 + 2];
        float dx = verts[(size_t)nbrow * 3 + 0] - cx;
        float dy = verts[(size_t)nbrow * 3 + 1] - cy;
        float dz = verts[(size_t)nbrow * 3 + 2] - cz;
        float nrm = sqrtf(dx * dx + dy * dy + dz * dz) + 1e-12f;
        float inv = 1.0f / nrm;
        dnx = dx * inv; dny = dy * inv; dnz = dz * inv;
    }
    int m1 = lane, m2 = lane + 64;
    float ax = dirs[m1], ay = dirs[128 + m1], az = dirs[256 + m1];
    float i1 = 1.0f / (sqrtf(ax * ax + ay * ay + az * az) + 1e-12f);
    ax *= i1; ay *= i1; az *= i1;
    float bx = dirs[m2], by = dirs[128 + m2], bz = dirs[256 + m2];
    float i2 = 1.0f / (sqrtf(bx * bx + by * by + bz * bz) + 1e-12f);
    bx *= i2; by *= i2; bz *= i2;

    float mx1 = -INFINITY, mx2 = -INFINITY;
    for (int k = 0; k < 32; ++k) {
        float ex = __shfl(dnx, k, 64);
        float ey = __shfl(dny, k, 64);
        float ez = __shfl(dnz, k, 64);
        int nr = __shfl(nbrow, k, 64);
        const float* fr = fout + (size_t)nr * 160 + 32;
        float t1 = fmaxf(ex * ax + ey * ay + ez * az, 0.0f);
        float t2 = fmaxf(ex * bx + ey * by + ez * bz, 0.0f);
        mx1 = fmaxf(mx1, t1 * fr[m1]);
        mx2 = fmaxf(mx2, t2 * fr[m2]);
    }
    float part = mx1 + mx2;
    float tot = part + __shfl_xor(part, 32, 64);
    if (lane < 32) {
        float c = fout[(size_t)wid * 160 + lane];
        float val = c + tot;
        if (do_relu) val = fmaxf(val, 0.0f);
        outF[(size_t)wid * Cw + coff + lane] = val;
    }
}

// ---------------------------------------------------------------------------
// conv11 aggregation: cout=1024. One block per (b,v), XCD-swizzled.
// fout row (bf16) = [center(1024) | supp(4096)], stride 5120.
// ---------------------------------------------------------------------------
__global__ void conv_agg_big_kernel(const int* __restrict__ idx,
                                    const float* __restrict__ verts,
                                    const __hip_bfloat16* __restrict__ fout,
                                    const float* __restrict__ dirs,
                                    float* __restrict__ G,
                                    int V, int B)
{
    __shared__ float dnS[32][3];
    __shared__ int nbS[32];
    int blk = blockIdx.x;
    int b = (blk & 7) >> 1;
    int v = ((blk >> 3) << 1) | (blk & 1);
    int row = b * V + v;
    int tid = threadIdx.x;

    if (tid < 32) {
        int nb = idx[(size_t)row * 32 + tid];
        int nbrow = b * V + nb;
        float cx = verts[(size_t)row * 3 + 0];
        float cy = verts[(size_t)row * 3 + 1];
        float cz = verts[(size_t)row * 3 + 2];
        float dx = verts[(size_t)nbrow * 3 + 0] - cx;
        float dy = verts[(size_t)nbrow * 3 + 1] - cy;
        float dz = verts[(size_t)nbrow * 3 + 2] - cz;
        float nrm = sqrtf(dx * dx + dy * dy + dz * dz) + 1e-12f;
        float inv = 1.0f / nrm;
        dnS[tid][0] = dx * inv; dnS[tid][1] = dy * inv; dnS[tid][2] = dz * inv;
        nbS[tid] = nbrow;
    }
    __syncthreads();

    float sdx[16], sdy[16], sdz[16], mx[16];
    for (int p = 0; p < 16; ++p) {
        int pair = p * 256 + tid;
        float ax = dirs[pair], ay = dirs[4096 + pair], az = dirs[8192 + pair];
        float inv = 1.0f / (sqrtf(ax * ax + ay * ay + az * az) + 1e-12f);
        sdx[p] = ax * inv; sdy[p] = ay * inv; sdz[p] = az * inv;
        mx[p] = -INFINITY;
    }
    for (int k = 0; k < 32; ++k) {
        float ex = dnS[k][0], ey = dnS[k][1], ez = dnS[k][2];
        const __hip_bfloat16* fr = fout + (size_t)nbS[k] * 5120 + 1024;
        for (int p = 0; p < 16; ++p) {
            float th = fmaxf(ex * sdx[p] + ey * sdy[p] + ez * sdz[p], 0.0f);
            float s = __bfloat162float(fr[p * 256 + tid]);
            mx[p] = fmaxf(mx[p], th * s);
        }
    }
    for (int q = 0; q < 4; ++q) {
        float val = ((mx[q] + mx[4 + q]) + mx[8 + q]) + mx[12 + q];
        int oo = q * 256 + tid;
        float c = __bfloat162float(fout[(size_t)row * 5120 + oo]);
        G[(size_t)row * 1024 + oo] = c + val;
    }
}

// ---------------------------------------------------------------------------
// Fused pool: per pooled vertex (one wave): query_ball(K=4) + channel max +
// verts copy. Exact same membership arithmetic as qb_kernel.
// ---------------------------------------------------------------------------
__global__ void pool_fused_kernel(const float* __restrict__ verts, int Vp, int Vh, int B,
                                  float r2, const float* __restrict__ Fin, int CwIn,
                                  float* __restrict__ Fout, int CwOut, int C,
                                  float* __restrict__ vout)
{
    int wid = (blockIdx.x * blockDim.x + threadIdx.x) >> 6;
    int lane = threadIdx.x & 63;
    int nq = B * Vh;
    if (wid >= nq) return;
    int b = wid / Vh;
    int v = wid - b * Vh;

    const float* q = verts + (size_t)(b * Vp + v) * 3;
    float qx = q[0], qy = q[1], qz = q[2];
    float qn = frn_add(frn_add(frn_mul(qx, qx), frn_mul(qy, qy)), frn_mul(qz, qz));
    const float* pts = verts + (size_t)b * Vp * 3;

    int ids[4];
    int count = 0;
    for (int base = 0; base < Vp && count < 4; base += 64) {
        int j = base + lane;
        bool in = false;
        if (j < Vp) {
            float px = pts[j * 3 + 0], py = pts[j * 3 + 1], pz = pts[j * 3 + 2];
            float pn = frn_add(frn_add(frn_mul(px, px), frn_mul(py, py)), frn_mul(pz, pz));
            float dt = frn_add(frn_add(frn_mul(qx, px), frn_mul(qy, py)), frn_mul(qz, pz));
            float d = __fsub_rn(frn_add(qn, pn), frn_mul(2.0f, dt));
            in = !(d > r2);
        }
        unsigned long long mask = __ballot(in);
        while (mask != 0ull && count < 4) {
            int jj = (int)__ffsll((long long)mask) - 1;
            ids[count++] = base + jj;
            mask &= mask - 1ull;
        }
    }
    for (int k = count; k < 4; ++k) ids[k] = ids[0];

    const float* r0 = Fin + (size_t)(b * Vp + ids[0]) * CwIn;
    const float* r1 = Fin + (size_t)(b * Vp + ids[1]) * CwIn;
    const float* r2p = Fin + (size_t)(b * Vp + ids[2]) * CwIn;
    const float* r3 = Fin + (size_t)(b * Vp + ids[3]) * CwIn;
    for (int c = lane; c < C; c += 64) {
        float m = fmaxf(fmaxf(r0[c], r1[c]), fmaxf(r2p[c], r3[c]));
        Fout[(size_t)wid * CwOut + c] = m;
    }
    if (lane < 3) vout[(size_t)wid * 3 + lane] = q[lane];
}

// ---------------------------------------------------------------------------
// Head
// ---------------------------------------------------------------------------
__global__ void gmax_kernel(const float* __restrict__ G, float* __restrict__ gm,
                            int V, int B)
{
    int t = blockIdx.x * blockDim.x + threadIdx.x;
    if (t >= B * 1024) return;
    int b = t >> 10;
    int c = t & 1023;
    float m = -INFINITY;
    for (int v = 0; v < V; ++v)
        m = fmaxf(m, G[((size_t)b * V + v) * 1024 + c]);
    gm[t] = m;
}

__global__ __launch_bounds__(256)
void head_kernel(const float* __restrict__ gm, const float* __restrict__ w1,
                 const float* __restrict__ b1_,
                 const float* __restrict__ bn_g, const float* __restrict__ bn_b,
                 const float* __restrict__ bn_m, const float* __restrict__ bn_v,
                 const float* __restrict__ w2, const float* __restrict__ b2_,
                 float* __restrict__ out)
{
    __shared__ float gs[1024];
    __shared__ float hs[256];
    int b = blockIdx.x;
    int j = threadIdx.x;
    for (int t = j; t < 1024; t += 256) gs[t] = gm[b * 1024 + t];
    __syncthreads();
    float acc = 0.0f;
    for (int k = 0; k < 1024; ++k) acc = fmaf(gs[k], w1[(size_t)k * 256 + j], acc);
    acc += b1_[j];
    acc = (acc - bn_m[j]) / sqrtf(bn_v[j] + 1e-5f) * bn_g[j] + bn_b[j];
    hs[j] = fmaxf(acc, 0.0f);
    __syncthreads();
    if (j < 40) {
        float a2 = 0.0f;
        for (int k = 0; k < 256; ++k) a2 = fmaf(hs[k], w2[(size_t)k * 40 + j], a2);
        out[b * 40 + j] = a2 + b2_[j];
    }
}

// ---------------------------------------------------------------------------
static inline int wblocks(int waves) { return (waves + 3) / 4; }
static inline int tblocks(int threads) { return (threads + 255) / 256; }
static inline dim3 ggrid(int M, int N) { return dim3(M / 64, (N + 63) / 64); }

extern "C" void kernel_launch(void* const* d_in, const int* in_sizes, int n_in,
                              void* d_out, int out_size, void* d_ws, size_t ws_size,
                              hipStream_t stream)
{
    const int B = 4;
    const float* verts1 = (const float*)d_in[0];
    const float* surf_dirs = (const float*)d_in[1];
    const float* w1 = (const float*)d_in[2];
    const float* b1 = (const float*)d_in[3];
    const float* d1 = (const float*)d_in[4];
    const float* w3 = (const float*)d_in[5];
    const float* b3 = (const float*)d_in[6];
    const float* d3 = (const float*)d_in[7];
    const float* w4 = (const float*)d_in[8];
    const float* b4 = (const float*)d_in[9];
    const float* d4 = (const float*)d_in[10];
    const float* w6 = (const float*)d_in[11];
    const float* b6 = (const float*)d_in[12];
    const float* d6 = (const float*)d_in[13];
    const float* w7 = (const float*)d_in[14];
    const float* b7 = (const float*)d_in[15];
    const float* d7 = (const float*)d_in[16];
    const float* w8 = (const float*)d_in[17];
    const float* b8 = (const float*)d_in[18];
    const float* d8 = (const float*)d_in[19];
    const float* w9 = (const float*)d_in[20];
    const float* b9 = (const float*)d_in[21];
    const float* d9 = (const float*)d_in[22];
    const float* w10 = (const float*)d_in[23];
    const float* b10 = (const float*)d_in[24];
    const float* d10 = (const float*)d_in[25];
    const float* w11 = (const float*)d_in[26];
    const float* b11 = (const float*)d_in[27];
    const float* d11 = (const float*)d_in[28];
    const float* fc1_w = (const float*)d_in[29];
    const float* fc1_b = (const float*)d_in[30];
    const float* bn_g = (const float*)d_in[31];
    const float* bn_b = (const float*)d_in[32];
    const float* bn_m = (const float*)d_in[33];
    const float* bn_v = (const float*)d_in[34];
    const float* fc2_w = (const float*)d_in[35];
    const float* fc2_b = (const float*)d_in[36];
    (void)in_sizes; (void)n_in; (void)out_size; (void)ws_size;

    float* ws = (float*)d_ws;
    size_t off = 0;
    auto alloc = [&](size_t n) { float* p = ws + off; off += n; return p; };
    float* fout = alloc(4 * 256 * 5120);    // GEMM scratch (max = conv11; bf16 fits in same region)
    int* idx = (int*)alloc(4 * 4096 * 32);
    float* F1 = alloc(4 * 4096 * 64);
    float* L2 = alloc(4 * 2048 * 128);
    float* L3 = alloc(4 * 1024 * 192);
    float* L4 = alloc(4 * 512 * 256);
    float* L5 = alloc(4 * 256 * 288);
    float* G = alloc(4 * 256 * 1024);
    float* v2 = alloc(4 * 2048 * 3);
    float* v3 = alloc(4 * 1024 * 3);
    float* v4 = alloc(4 * 512 * 3);
    float* v5 = alloc(4 * 256 * 3);
    float* gm = alloc(4 * 1024);

    // ---- Level 1 (V=4096, r=0.2) ----
    qb_kernel<<<wblocks(B * 4096), 256, 0, stream>>>(verts1, 4096, 4096, B, 0.04f, 32, idx);
    conv_surface_kernel<<<wblocks(B * 4096), 256, 0, stream>>>(idx, verts1, surf_dirs, F1, 64, 4096, B);
    gemm_tiled_kernel<float><<<ggrid(B * 4096, 160), 256, 0, stream>>>(F1, 64, 32, w1, b1, 160, fout);
    conv_agg32_kernel<<<B * 4096 / 4, 256, 0, stream>>>(idx, verts1, fout, d1, F1, 64, 32, 4096, 1);
    pool_fused_kernel<<<wblocks(B * 2048), 256, 0, stream>>>(verts1, 4096, 2048, B, 0.04f, F1, 64, L2, 128, 64, v2);

    // ---- Level 2 (V=2048, r=0.4) ----
    qb_kernel<<<wblocks(B * 2048), 256, 0, stream>>>(v2, 2048, 2048, B, 0.16f, 32, idx);
    gemm_tiled_kernel<float><<<ggrid(B * 2048, 160), 256, 0, stream>>>(L2, 128, 64, w3, b3, 160, fout);
    conv_agg32_kernel<<<B * 2048 / 4, 256, 0, stream>>>(idx, v2, fout, d3, L2, 128, 64, 2048, 1);
    gemm_tiled_kernel<float><<<ggrid(B * 2048, 160), 256, 0, stream>>>(L2, 128, 96, w4, b4, 160, fout);
    conv_agg32_kernel<<<B * 2048 / 4, 256, 0, stream>>>(idx, v2, fout, d4, L2, 128, 96, 2048, 1);
    pool_fused_kernel<<<wblocks(B * 1024), 256, 0, stream>>>(v2, 2048, 1024, B, 0.16f, L2, 128, L3, 192, 128, v3);

    // ---- Level 3 (V=1024, r=0.6) ----
    qb_kernel<<<wblocks(B * 1024), 256, 0, stream>>>(v3, 1024, 1024, B, 0.36f, 32, idx);
    gemm_tiled_kernel<float><<<ggrid(B * 1024, 160), 256, 0, stream>>>(L3, 192, 128, w6, b6, 160, fout);
    conv_agg32_kernel<<<B * 1024 / 4, 256, 0, stream>>>(idx, v3, fout, d6, L3, 192, 128, 1024, 1);
    gemm_tiled_kernel<float><<<ggrid(B * 1024, 160), 256, 0, stream>>>(L3, 192, 160, w7, b7, 160, fout);
    conv_agg32_kernel<<<B * 1024 / 4, 256, 0, stream>>>(idx, v3, fout, d7, L3, 192, 160, 1024, 1);
    pool_fused_kernel<<<wblocks(B * 512), 256, 0, stream>>>(v3, 1024, 512, B, 0.36f, L3, 192, L4, 256, 192, v4);

    // ---- Level 4 (V=512, r=0.8) ----
    qb_kernel<<<wblocks(B * 512), 256, 0, stream>>>(v4, 512, 512, B, 0.64f, 32, idx);
    gemm_tiled_kernel<float><<<ggrid(B * 512, 160), 256, 0, stream>>>(L4, 256, 192, w8, b8, 160, fout);
    conv_agg32_kernel<<<B * 512 / 4, 256, 0, stream>>>(idx, v4, fout, d8, L4, 256, 192, 512, 1);
    gemm_tiled_kernel<float><<<ggrid(B * 512, 160), 256, 0, stream>>>(L4, 256, 224, w9, b9, 160, fout);
    conv_agg32_kernel<<<B * 512 / 4, 256, 0, stream>>>(idx, v4, fout, d9, L4, 256, 224, 512, 1);
    pool_fused_kernel<<<wblocks(B * 256), 256, 0, stream>>>(v4, 512, 256, B, 0.64f, L4, 256, L5, 288, 256, v5);

    // ---- Level 5 (V=256, r=1.0) ----
    qb_kernel<<<wblocks(B * 256), 256, 0, stream>>>(v5, 256, 256, B, 1.0f, 32, idx);
    gemm_tiled_kernel<float><<<ggrid(B * 256, 160), 256, 0, stream>>>(L5, 288, 256, w10, b10, 160, fout);
    conv_agg32_kernel<<<B * 256 / 4, 256, 0, stream>>>(idx, v5, fout, d10, L5, 288, 256, 256, 1);
    __hip_bfloat16* fout_bf = (__hip_bfloat16*)fout;
    gemm_tiled_kernel<__hip_bfloat16><<<ggrid(B * 256, 5120), 256, 0, stream>>>(L5, 288, 288, w11, b11, 5120, fout_bf);
    conv_agg_big_kernel<<<B * 256, 256, 0, stream>>>(idx, v5, fout_bf, d11, G, 256, B);

    // ---- Head ----
    gmax_kernel<<<tblocks(B * 1024), 256, 0, stream>>>(G, gm, 256, B);
    head_kernel<<<B, 256, 0, stream>>>(gm, fc1_w, fc1_b, bn_g, bn_b, bn_m, bn_v, fc2_w, fc2_b, (float*)d_out);
}

// Round 5
// 551.450 us; speedup vs baseline: 2.9108x; 1.0042x over previous
//
#include <hip/hip_runtime.h>
#include <hip/hip_bf16.h>
#include <math.h>

#define DEV __device__ __forceinline__

DEV float frn_mul(float a, float b) { return __fmul_rn(a, b); }
DEV float frn_add(float a, float b) { return __fadd_rn(a, b); }

union BFU { __hip_bfloat16 h; unsigned short u; };

// ---------------------------------------------------------------------------
// query_ball: one wave (64 lanes) per query. Keeps the K smallest-index
// in-range points (scan ascending with ballot), pads remainder with first.
// ---------------------------------------------------------------------------
__global__ void qb_kernel(const float* __restrict__ verts, int Vp, int Vq, int B,
                          float r2, int K, int* __restrict__ idx_out)
{
    int wid = (blockIdx.x * blockDim.x + threadIdx.x) >> 6;
    int lane = threadIdx.x & 63;
    int nq = B * Vq;
    if (wid >= nq) return;
    int b = wid / Vq;
    int v = wid - b * Vq;

    const float* q = verts + (size_t)(b * Vp + v) * 3;
    float qx = q[0], qy = q[1], qz = q[2];
    float qn = frn_add(frn_add(frn_mul(qx, qx), frn_mul(qy, qy)), frn_mul(qz, qz));
    const float* pts = verts + (size_t)b * Vp * 3;
    int* row = idx_out + (size_t)wid * K;

    int count = 0;
    int first = -1;
    for (int base = 0; base < Vp && count < K; base += 64) {
        int j = base + lane;
        bool in = false;
        if (j < Vp) {
            float px = pts[j * 3 + 0], py = pts[j * 3 + 1], pz = pts[j * 3 + 2];
            float pn = frn_add(frn_add(frn_mul(px, px), frn_mul(py, py)), frn_mul(pz, pz));
            float dt = frn_add(frn_add(frn_mul(qx, px), frn_mul(qy, py)), frn_mul(qz, pz));
            float d = __fsub_rn(frn_add(qn, pn), frn_mul(2.0f, dt));
            in = !(d > r2);
        }
        unsigned long long mask = __ballot(in);
        if (first < 0 && mask != 0ull)
            first = base + (int)__ffsll((long long)mask) - 1;
        int pos = count + (int)__popcll(mask & ((1ull << lane) - 1ull));
        if (in && pos < K) row[pos] = j;
        count += (int)__popcll(mask);
    }
    int cnt = count < K ? count : K;
    for (int t = cnt + lane; t < K; t += 64) row[t] = first;
}

// ---------------------------------------------------------------------------
// conv_surface: one wave per (b,v). o=32, S=4, K=32.
// ---------------------------------------------------------------------------
__global__ void conv_surface_kernel(const int* __restrict__ idx,
                                    const float* __restrict__ verts,
                                    const float* __restrict__ dirs, // (3,128)
                                    float* __restrict__ outF, int Cw,
                                    int V, int B)
{
    int wid = (blockIdx.x * blockDim.x + threadIdx.x) >> 6;
    int lane = threadIdx.x & 63;
    int n = B * V;
    if (wid >= n) return;
    int b = wid / V;

    float dnx, dny, dnz;
    {
        int k = lane & 31;
        int nb = idx[(size_t)wid * 32 + k];
        int nbrow = b * V + nb;
        float cx = verts[(size_t)wid * 3 + 0];
        float cy = verts[(size_t)wid * 3 + 1];
        float cz = verts[(size_t)wid * 3 + 2];
        float dx = verts[(size_t)nbrow * 3 + 0] - cx;
        float dy = verts[(size_t)nbrow * 3 + 1] - cy;
        float dz = verts[(size_t)nbrow * 3 + 2] - cz;
        float nrm = sqrtf(dx * dx + dy * dy + dz * dz) + 1e-12f;
        float inv = 1.0f / nrm;
        dnx = dx * inv; dny = dy * inv; dnz = dz * inv;
    }
    int m1 = lane, m2 = lane + 64;
    float ax = dirs[m1], ay = dirs[128 + m1], az = dirs[256 + m1];
    float i1 = 1.0f / (sqrtf(ax * ax + ay * ay + az * az) + 1e-12f);
    ax *= i1; ay *= i1; az *= i1;
    float bx = dirs[m2], by = dirs[128 + m2], bz = dirs[256 + m2];
    float i2 = 1.0f / (sqrtf(bx * bx + by * by + bz * bz) + 1e-12f);
    bx *= i2; by *= i2; bz *= i2;

    float mx1 = -INFINITY, mx2 = -INFINITY;
    for (int k = 0; k < 32; ++k) {
        float ex = __shfl(dnx, k, 64);
        float ey = __shfl(dny, k, 64);
        float ez = __shfl(dnz, k, 64);
        float t1 = fmaxf(ex * ax + ey * ay + ez * az, 0.0f);
        float t2 = fmaxf(ex * bx + ey * by + ez * bz, 0.0f);
        mx1 = fmaxf(mx1, t1);
        mx2 = fmaxf(mx2, t2);
    }
    float part = mx1 + mx2;
    float tot = part + __shfl_xor(part, 32, 64);
    if (lane < 32) {
        outF[(size_t)wid * Cw + lane] = fmaxf(tot, 0.0f);
    }
}

// ---------------------------------------------------------------------------
// Tiled GEMM (64x64, 4x4 micro): for the small-N layer GEMMs.
// ---------------------------------------------------------------------------
template <typename OT>
__global__ __launch_bounds__(256)
void gemm_tiled_kernel(const float* __restrict__ feat, int Cw, int cin,
                       const float* __restrict__ w, const float* __restrict__ bias,
                       int N, OT* __restrict__ fout)
{
    __shared__ float As[64][36];
    __shared__ float Bs[32][68];

    int m0 = blockIdx.x * 64;
    int n0 = blockIdx.y * 64;
    int tid = threadIdx.x;
    int tx = tid & 15, ty = tid >> 4;

    float acc[4][4];
#pragma unroll
    for (int i = 0; i < 4; ++i)
#pragma unroll
        for (int j = 0; j < 4; ++j) acc[i][j] = 0.0f;

    for (int k0 = 0; k0 < cin; k0 += 32) {
#pragma unroll
        for (int i = 0; i < 2; ++i) {
            int qq = tid + i * 256;
            int row = qq >> 3, c = qq & 7;
            float4 v = *(const float4*)&feat[(size_t)(m0 + row) * Cw + k0 + 4 * c];
            *(float4*)&As[row][4 * c] = v;
        }
#pragma unroll
        for (int i = 0; i < 2; ++i) {
            int qq = tid + i * 256;
            int kr = qq >> 4, c = qq & 15;
            int n = n0 + 4 * c;
            float4 v = make_float4(0.0f, 0.0f, 0.0f, 0.0f);
            if (n < N) v = *(const float4*)&w[(size_t)(k0 + kr) * N + n];
            *(float4*)&Bs[kr][4 * c] = v;
        }
        __syncthreads();

#pragma unroll
        for (int kt = 0; kt < 32; kt += 4) {
            float4 av4[4], bv4[4];
#pragma unroll
            for (int i = 0; i < 4; ++i) av4[i] = *(const float4*)&As[ty * 4 + i][kt];
#pragma unroll
            for (int r = 0; r < 4; ++r) bv4[r] = *(const float4*)&Bs[kt + r][tx * 4];
            const float* a = (const float*)av4;
            const float* bb = (const float*)bv4;
#pragma unroll
            for (int i = 0; i < 4; ++i)
#pragma unroll
                for (int r = 0; r < 4; ++r)
#pragma unroll
                    for (int j = 0; j < 4; ++j)
                        acc[i][j] = fmaf(a[i * 4 + r], bb[r * 4 + j], acc[i][j]);
        }
        __syncthreads();
    }

    int n = n0 + tx * 4;
    if (n < N) {
        float b0 = bias[n + 0], b1 = bias[n + 1], b2 = bias[n + 2], b3 = bias[n + 3];
#pragma unroll
        for (int i = 0; i < 4; ++i) {
            int m = m0 + ty * 4 + i;
            if constexpr (__is_same(OT, float)) {
                float4 o;
                o.x = acc[i][0] + b0;
                o.y = acc[i][1] + b1;
                o.z = acc[i][2] + b2;
                o.w = acc[i][3] + b3;
                *(float4*)&fout[(size_t)m * N + n] = o;
            } else {
                BFU t0, t1, t2, t3;
                t0.h = __float2bfloat16(acc[i][0] + b0);
                t1.h = __float2bfloat16(acc[i][1] + b1);
                t2.h = __float2bfloat16(acc[i][2] + b2);
                t3.h = __float2bfloat16(acc[i][3] + b3);
                ushort4 o;
                o.x = t0.u; o.y = t1.u; o.z = t2.u; o.w = t3.u;
                *(ushort4*)&fout[(size_t)m * N + n] = o;
            }
        }
    }
}

// ---------------------------------------------------------------------------
// Big tiled GEMM (128x128 tile, 8x8 micro as 2x2 blocks of 4x4) — conv11.
// A transposed into LDS [k][m]; f4 LDS reads are 2-way-conflict-free.
// M % 128 == 0; cin % 32 == 0.
// ---------------------------------------------------------------------------
template <typename OT>
__global__ __launch_bounds__(256)
void gemm_tiled128_kernel(const float* __restrict__ feat, int Cw, int cin,
                          const float* __restrict__ w, const float* __restrict__ bias,
                          int N, OT* __restrict__ fout)
{
    __shared__ float As[32][132]; // [k][m]
    __shared__ float Bs[32][132]; // [k][n]

    int m0 = blockIdx.x * 128;
    int n0 = blockIdx.y * 128;
    int tid = threadIdx.x;
    int tx = tid & 15, ty = tid >> 4;

    float acc[2][4][2][4];
#pragma unroll
    for (int ih = 0; ih < 2; ++ih)
#pragma unroll
        for (int i = 0; i < 4; ++i)
#pragma unroll
            for (int jh = 0; jh < 2; ++jh)
#pragma unroll
                for (int j = 0; j < 4; ++j) acc[ih][i][jh][j] = 0.0f;

    for (int k0 = 0; k0 < cin; k0 += 32) {
        // stage A (transpose): 128 rows x 32 k
#pragma unroll
        for (int i = 0; i < 4; ++i) {
            int qq = tid + i * 256;          // 0..1023
            int row = qq >> 3, c = qq & 7;   // row 0..127, f4 idx 0..7
            float4 v = *(const float4*)&feat[(size_t)(m0 + row) * Cw + k0 + 4 * c];
            As[4 * c + 0][row] = v.x;
            As[4 * c + 1][row] = v.y;
            As[4 * c + 2][row] = v.z;
            As[4 * c + 3][row] = v.w;
        }
        // stage B: 32 k x 128 n
#pragma unroll
        for (int i = 0; i < 4; ++i) {
            int qq = tid + i * 256;
            int kr = qq >> 5, c = qq & 31;
            int n = n0 + 4 * c;
            float4 v = make_float4(0.0f, 0.0f, 0.0f, 0.0f);
            if (n < N) v = *(const float4*)&w[(size_t)(k0 + kr) * N + n];
            *(float4*)&Bs[kr][4 * c] = v;
        }
        __syncthreads();

#pragma unroll
        for (int k = 0; k < 32; ++k) {
            float4 a0 = *(const float4*)&As[k][ty * 4];
            float4 a1 = *(const float4*)&As[k][64 + ty * 4];
            float4 b0 = *(const float4*)&Bs[k][tx * 4];
            float4 b1 = *(const float4*)&Bs[k][64 + tx * 4];
            float a[2][4] = {{a0.x, a0.y, a0.z, a0.w}, {a1.x, a1.y, a1.z, a1.w}};
            float bb[2][4] = {{b0.x, b0.y, b0.z, b0.w}, {b1.x, b1.y, b1.z, b1.w}};
#pragma unroll
            for (int ih = 0; ih < 2; ++ih)
#pragma unroll
                for (int i = 0; i < 4; ++i)
#pragma unroll
                    for (int jh = 0; jh < 2; ++jh)
#pragma unroll
                        for (int j = 0; j < 4; ++j)
                            acc[ih][i][jh][j] = fmaf(a[ih][i], bb[jh][j], acc[ih][i][jh][j]);
        }
        __syncthreads();
    }

#pragma unroll
    for (int ih = 0; ih < 2; ++ih)
#pragma unroll
        for (int i = 0; i < 4; ++i) {
            int m = m0 + ih * 64 + ty * 4 + i;
#pragma unroll
            for (int jh = 0; jh < 2; ++jh) {
                int n = n0 + jh * 64 + tx * 4;
                if (n < N) {
                    float o0 = acc[ih][i][jh][0] + bias[n + 0];
                    float o1 = acc[ih][i][jh][1] + bias[n + 1];
                    float o2 = acc[ih][i][jh][2] + bias[n + 2];
                    float o3 = acc[ih][i][jh][3] + bias[n + 3];
                    if constexpr (__is_same(OT, float)) {
                        float4 o; o.x = o0; o.y = o1; o.z = o2; o.w = o3;
                        *(float4*)&fout[(size_t)m * N + n] = o;
                    } else {
                        BFU t0, t1, t2, t3;
                        t0.h = __float2bfloat16(o0);
                        t1.h = __float2bfloat16(o1);
                        t2.h = __float2bfloat16(o2);
                        t3.h = __float2bfloat16(o3);
                        ushort4 o; o.x = t0.u; o.y = t1.u; o.z = t2.u; o.w = t3.u;
                        *(ushort4*)&fout[(size_t)m * N + n] = o;
                    }
                }
            }
        }
}

// ---------------------------------------------------------------------------
// conv_layer aggregation, cout=32. One wave per (b,v), XCD-swizzled:
// batch b's blocks pinned to XCDs {2b,2b+1} so fout slice is L2-resident.
// Grid must be exactly B*V/4 blocks of 256 threads.
// ---------------------------------------------------------------------------
__global__ void conv_agg32_kernel(const int* __restrict__ idx,
                                  const float* __restrict__ verts,
                                  const float* __restrict__ fout,
                                  const float* __restrict__ dirs, // (3,128)
                                  float* __restrict__ outF, int Cw, int coff,
                                  int V, int do_relu)
{
    int blk = blockIdx.x;
    int b = (blk & 7) >> 1;
    int j = ((blk >> 3) << 1) | (blk & 1);
    int wid = b * V + j * 4 + (int)(threadIdx.x >> 6);
    int lane = threadIdx.x & 63;

    float dnx, dny, dnz;
    int nbrow;
    {
        int k = lane & 31;
        int nb = idx[(size_t)wid * 32 + k];
        nbrow = b * V + nb;
        float cx = verts[(size_t)wid * 3 + 0];
        float cy = verts[(size_t)wid * 3 + 1];
        float cz = verts[(size_t)wid * 3 + 2];
        float dx = verts[(size_t)nbrow * 3 + 0] - cx;
        float dy = verts[(size_t)nbrow * 3 + 1] - cy;
        float dz = verts[(size_t)nbrow * 3 + 2] - cz;
        float nrm = sqrtf(dx * dx + dy * dy + dz * dz) + 1e-12f;
        float inv = 1.0f / nrm;
        dnx = dx * inv; dny = dy * inv; dnz = dz * inv;
    }
    int m1 = lane, m2 = lane + 64;
    float ax = dirs[m1], ay = dirs[128 + m1], az = dirs[256 + m1];
    float i1 = 1.0f / (sqrtf(ax * ax + ay * ay + az * az) + 1e-12f);
    ax *= i1; ay *= i1; az *= i1;
    float bx = dirs[m2], by = dirs[128 + m2], bz = dirs[256 + m2];
    float i2 = 1.0f / (sqrtf(bx * bx + by * by + bz * bz) + 1e-12f);
    bx *= i2; by *= i2; bz *= i2;

    float mx1 = -INFINITY, mx2 = -INFINITY;
    for (int k = 0; k < 32; ++k) {
        float ex = __shfl(dnx, k, 64);
        float ey = __shfl(dny, k, 64);
        float ez = __shfl(dnz, k, 64);
        int nr = __shfl(nbrow, k, 64);
        const float* fr = fout + (size_t)nr * 160 + 32;
        float t1 = fmaxf(ex * ax + ey * ay + ez * az, 0.0f);
        float t2 = fmaxf(ex * bx + ey * by + ez * bz, 0.0f);
        mx1 = fmaxf(mx1, t1 * fr[m1]);
        mx2 = fmaxf(mx2, t2 * fr[m2]);
    }
    float part = mx1 + mx2;
    float tot = part + __shfl_xor(part, 32, 64);
    if (lane < 32) {
        float c = fout[(size_t)wid * 160 + lane];
        float val = c + tot;
        if (do_relu) val = fmaxf(val, 0.0f);
        outF[(size_t)wid * Cw + coff + lane] = val;
    }
}

// ---------------------------------------------------------------------------
// conv11 aggregation: cout=1024. One block per (b,v), XCD-swizzled.
// fout row (bf16) = [center(1024) | supp(4096)], stride 5120.
// ---------------------------------------------------------------------------
__global__ void conv_agg_big_kernel(const int* __restrict__ idx,
                                    const float* __restrict__ verts,
                                    const __hip_bfloat16* __restrict__ fout,
                                    const float* __restrict__ dirs,
                                    float* __restrict__ G,
                                    int V, int B)
{
    __shared__ float dnS[32][3];
    __shared__ int nbS[32];
    int blk = blockIdx.x;
    int b = (blk & 7) >> 1;
    int v = ((blk >> 3) << 1) | (blk & 1);
    int row = b * V + v;
    int tid = threadIdx.x;

    if (tid < 32) {
        int nb = idx[(size_t)row * 32 + tid];
        int nbrow = b * V + nb;
        float cx = verts[(size_t)row * 3 + 0];
        float cy = verts[(size_t)row * 3 + 1];
        float cz = verts[(size_t)row * 3 + 2];
        float dx = verts[(size_t)nbrow * 3 + 0] - cx;
        float dy = verts[(size_t)nbrow * 3 + 1] - cy;
        float dz = verts[(size_t)nbrow * 3 + 2] - cz;
        float nrm = sqrtf(dx * dx + dy * dy + dz * dz) + 1e-12f;
        float inv = 1.0f / nrm;
        dnS[tid][0] = dx * inv; dnS[tid][1] = dy * inv; dnS[tid][2] = dz * inv;
        nbS[tid] = nbrow;
    }
    __syncthreads();

    float sdx[16], sdy[16], sdz[16], mx[16];
    for (int p = 0; p < 16; ++p) {
        int pair = p * 256 + tid;
        float ax = dirs[pair], ay = dirs[4096 + pair], az = dirs[8192 + pair];
        float inv = 1.0f / (sqrtf(ax * ax + ay * ay + az * az) + 1e-12f);
        sdx[p] = ax * inv; sdy[p] = ay * inv; sdz[p] = az * inv;
        mx[p] = -INFINITY;
    }
    for (int k = 0; k < 32; ++k) {
        float ex = dnS[k][0], ey = dnS[k][1], ez = dnS[k][2];
        const __hip_bfloat16* fr = fout + (size_t)nbS[k] * 5120 + 1024;
        for (int p = 0; p < 16; ++p) {
            float th = fmaxf(ex * sdx[p] + ey * sdy[p] + ez * sdz[p], 0.0f);
            float s = __bfloat162float(fr[p * 256 + tid]);
            mx[p] = fmaxf(mx[p], th * s);
        }
    }
    for (int q = 0; q < 4; ++q) {
        float val = ((mx[q] + mx[4 + q]) + mx[8 + q]) + mx[12 + q];
        int oo = q * 256 + tid;
        float c = __bfloat162float(fout[(size_t)row * 5120 + oo]);
        G[(size_t)row * 1024 + oo] = c + val;
    }
}

// ---------------------------------------------------------------------------
// Fused pool: per pooled vertex (one wave): query_ball(K=4) + channel max +
// verts copy.
// ---------------------------------------------------------------------------
__global__ void pool_fused_kernel(const float* __restrict__ verts, int Vp, int Vh, int B,
                                  float r2, const float* __restrict__ Fin, int CwIn,
                                  float* __restrict__ Fout, int CwOut, int C,
                                  float* __restrict__ vout)
{
    int wid = (blockIdx.x * blockDim.x + threadIdx.x) >> 6;
    int lane = threadIdx.x & 63;
    int nq = B * Vh;
    if (wid >= nq) return;
    int b = wid / Vh;
    int v = wid - b * Vh;

    const float* q = verts + (size_t)(b * Vp + v) * 3;
    float qx = q[0], qy = q[1], qz = q[2];
    float qn = frn_add(frn_add(frn_mul(qx, qx), frn_mul(qy, qy)), frn_mul(qz, qz));
    const float* pts = verts + (size_t)b * Vp * 3;

    int ids[4];
    int count = 0;
    for (int base = 0; base < Vp && count < 4; base += 64) {
        int j = base + lane;
        bool in = false;
        if (j < Vp) {
            float px = pts[j * 3 + 0], py = pts[j * 3 + 1], pz = pts[j * 3 + 2];
            float pn = frn_add(frn_add(frn_mul(px, px), frn_mul(py, py)), frn_mul(pz, pz));
            float dt = frn_add(frn_add(frn_mul(qx, px), frn_mul(qy, py)), frn_mul(qz, pz));
            float d = __fsub_rn(frn_add(qn, pn), frn_mul(2.0f, dt));
            in = !(d > r2);
        }
        unsigned long long mask = __ballot(in);
        while (mask != 0ull && count < 4) {
            int jj = (int)__ffsll((long long)mask) - 1;
            ids[count++] = base + jj;
            mask &= mask - 1ull;
        }
    }
    for (int k = count; k < 4; ++k) ids[k] = ids[0];

    const float* r0 = Fin + (size_t)(b * Vp + ids[0]) * CwIn;
    const float* r1 = Fin + (size_t)(b * Vp + ids[1]) * CwIn;
    const float* r2p = Fin + (size_t)(b * Vp + ids[2]) * CwIn;
    const float* r3 = Fin + (size_t)(b * Vp + ids[3]) * CwIn;
    for (int c = lane; c < C; c += 64) {
        float m = fmaxf(fmaxf(r0[c], r1[c]), fmaxf(r2p[c], r3[c]));
        Fout[(size_t)wid * CwOut + c] = m;
    }
    if (lane < 3) vout[(size_t)wid * 3 + lane] = q[lane];
}

// ---------------------------------------------------------------------------
// Head
// ---------------------------------------------------------------------------
__global__ void gmax_kernel(const float* __restrict__ G, float* __restrict__ gm,
                            int V, int B)
{
    int t = blockIdx.x * blockDim.x + threadIdx.x;
    if (t >= B * 1024) return;
    int b = t >> 10;
    int c = t & 1023;
    float m = -INFINITY;
    for (int v = 0; v < V; ++v)
        m = fmaxf(m, G[((size_t)b * V + v) * 1024 + c]);
    gm[t] = m;
}

// fc1 split: grid (8, B). Block 256 = 32 j x 8 k-chunks of 128.
__global__ __launch_bounds__(256)
void fc1_kernel(const float* __restrict__ gm, const float* __restrict__ w1,
                const float* __restrict__ b1_,
                const float* __restrict__ bn_g, const float* __restrict__ bn_b,
                const float* __restrict__ bn_m, const float* __restrict__ bn_v,
                float* __restrict__ h)
{
    __shared__ float gs[1024];
    __shared__ float red[8][32];
    int b = blockIdx.y;
    int j0 = blockIdx.x * 32;
    int t = threadIdx.x;
    for (int i = t; i < 1024; i += 256) gs[i] = gm[b * 1024 + i];
    __syncthreads();
    int jj = t & 31, kk = t >> 5;
    int j = j0 + jj;
    const float* wp = w1 + (size_t)(kk * 128) * 256 + j;
    float acc = 0.0f;
#pragma unroll 8
    for (int k = 0; k < 128; ++k)
        acc = fmaf(gs[kk * 128 + k], wp[(size_t)k * 256], acc);
    red[kk][jj] = acc;
    __syncthreads();
    if (t < 32) {
        float s = 0.0f;
#pragma unroll
        for (int q = 0; q < 8; ++q) s += red[q][t];
        int jw = j0 + t;
        s += b1_[jw];
        s = (s - bn_m[jw]) / sqrtf(bn_v[jw] + 1e-5f) * bn_g[jw] + bn_b[jw];
        h[b * 256 + jw] = fmaxf(s, 0.0f);
    }
}

__global__ void fc2_kernel(const float* __restrict__ h, const float* __restrict__ w2,
                           const float* __restrict__ b2_, float* __restrict__ out)
{
    __shared__ float hs[256];
    int b = blockIdx.x;
    int t = threadIdx.x;
    hs[t] = h[b * 256 + t];
    __syncthreads();
    if (t < 40) {
        float acc = 0.0f;
#pragma unroll 8
        for (int k = 0; k < 256; ++k) acc = fmaf(hs[k], w2[(size_t)k * 40 + t], acc);
        out[b * 40 + t] = acc + b2_[t];
    }
}

// ---------------------------------------------------------------------------
static inline int wblocks(int waves) { return (waves + 3) / 4; }
static inline int tblocks(int threads) { return (threads + 255) / 256; }
static inline dim3 ggrid(int M, int N) { return dim3(M / 64, (N + 63) / 64); }
static inline dim3 ggrid128(int M, int N) { return dim3(M / 128, (N + 127) / 128); }

extern "C" void kernel_launch(void* const* d_in, const int* in_sizes, int n_in,
                              void* d_out, int out_size, void* d_ws, size_t ws_size,
                              hipStream_t stream)
{
    const int B = 4;
    const float* verts1 = (const float*)d_in[0];
    const float* surf_dirs = (const float*)d_in[1];
    const float* w1 = (const float*)d_in[2];
    const float* b1 = (const float*)d_in[3];
    const float* d1 = (const float*)d_in[4];
    const float* w3 = (const float*)d_in[5];
    const float* b3 = (const float*)d_in[6];
    const float* d3 = (const float*)d_in[7];
    const float* w4 = (const float*)d_in[8];
    const float* b4 = (const float*)d_in[9];
    const float* d4 = (const float*)d_in[10];
    const float* w6 = (const float*)d_in[11];
    const float* b6 = (const float*)d_in[12];
    const float* d6 = (const float*)d_in[13];
    const float* w7 = (const float*)d_in[14];
    const float* b7 = (const float*)d_in[15];
    const float* d7 = (const float*)d_in[16];
    const float* w8 = (const float*)d_in[17];
    const float* b8 = (const float*)d_in[18];
    const float* d8 = (const float*)d_in[19];
    const float* w9 = (const float*)d_in[20];
    const float* b9 = (const float*)d_in[21];
    const float* d9 = (const float*)d_in[22];
    const float* w10 = (const float*)d_in[23];
    const float* b10 = (const float*)d_in[24];
    const float* d10 = (const float*)d_in[25];
    const float* w11 = (const float*)d_in[26];
    const float* b11 = (const float*)d_in[27];
    const float* d11 = (const float*)d_in[28];
    const float* fc1_w = (const float*)d_in[29];
    const float* fc1_b = (const float*)d_in[30];
    const float* bn_g = (const float*)d_in[31];
    const float* bn_b = (const float*)d_in[32];
    const float* bn_m = (const float*)d_in[33];
    const float* bn_v = (const float*)d_in[34];
    const float* fc2_w = (const float*)d_in[35];
    const float* fc2_b = (const float*)d_in[36];
    (void)in_sizes; (void)n_in; (void)out_size; (void)ws_size;

    float* ws = (float*)d_ws;
    size_t off = 0;
    auto alloc = [&](size_t n) { float* p = ws + off; off += n; return p; };
    float* fout = alloc(4 * 256 * 5120);
    int* idx = (int*)alloc(4 * 4096 * 32);
    float* F1 = alloc(4 * 4096 * 64);
    float* L2 = alloc(4 * 2048 * 128);
    float* L3 = alloc(4 * 1024 * 192);
    float* L4 = alloc(4 * 512 * 256);
    float* L5 = alloc(4 * 256 * 288);
    float* G = alloc(4 * 256 * 1024);
    float* v2 = alloc(4 * 2048 * 3);
    float* v3 = alloc(4 * 1024 * 3);
    float* v4 = alloc(4 * 512 * 3);
    float* v5 = alloc(4 * 256 * 3);
    float* gm = alloc(4 * 1024);
    float* hh = alloc(4 * 256);

    // ---- Level 1 (V=4096, r=0.2) ----
    qb_kernel<<<wblocks(B * 4096), 256, 0, stream>>>(verts1, 4096, 4096, B, 0.04f, 32, idx);
    conv_surface_kernel<<<wblocks(B * 4096), 256, 0, stream>>>(idx, verts1, surf_dirs, F1, 64, 4096, B);
    gemm_tiled_kernel<float><<<ggrid(B * 4096, 160), 256, 0, stream>>>(F1, 64, 32, w1, b1, 160, fout);
    conv_agg32_kernel<<<B * 4096 / 4, 256, 0, stream>>>(idx, verts1, fout, d1, F1, 64, 32, 4096, 1);
    pool_fused_kernel<<<wblocks(B * 2048), 256, 0, stream>>>(verts1, 4096, 2048, B, 0.04f, F1, 64, L2, 128, 64, v2);

    // ---- Level 2 (V=2048, r=0.4) ----
    qb_kernel<<<wblocks(B * 2048), 256, 0, stream>>>(v2, 2048, 2048, B, 0.16f, 32, idx);
    gemm_tiled_kernel<float><<<ggrid(B * 2048, 160), 256, 0, stream>>>(L2, 128, 64, w3, b3, 160, fout);
    conv_agg32_kernel<<<B * 2048 / 4, 256, 0, stream>>>(idx, v2, fout, d3, L2, 128, 64, 2048, 1);
    gemm_tiled_kernel<float><<<ggrid(B * 2048, 160), 256, 0, stream>>>(L2, 128, 96, w4, b4, 160, fout);
    conv_agg32_kernel<<<B * 2048 / 4, 256, 0, stream>>>(idx, v2, fout, d4, L2, 128, 96, 2048, 1);
    pool_fused_kernel<<<wblocks(B * 1024), 256, 0, stream>>>(v2, 2048, 1024, B, 0.16f, L2, 128, L3, 192, 128, v3);

    // ---- Level 3 (V=1024, r=0.6) ----
    qb_kernel<<<wblocks(B * 1024), 256, 0, stream>>>(v3, 1024, 1024, B, 0.36f, 32, idx);
    gemm_tiled_kernel<float><<<ggrid(B * 1024, 160), 256, 0, stream>>>(L3, 192, 128, w6, b6, 160, fout);
    conv_agg32_kernel<<<B * 1024 / 4, 256, 0, stream>>>(idx, v3, fout, d6, L3, 192, 128, 1024, 1);
    gemm_tiled_kernel<float><<<ggrid(B * 1024, 160), 256, 0, stream>>>(L3, 192, 160, w7, b7, 160, fout);
    conv_agg32_kernel<<<B * 1024 / 4, 256, 0, stream>>>(idx, v3, fout, d7, L3, 192, 160, 1024, 1);
    pool_fused_kernel<<<wblocks(B * 512), 256, 0, stream>>>(v3, 1024, 512, B, 0.36f, L3, 192, L4, 256, 192, v4);

    // ---- Level 4 (V=512, r=0.8) ----
    qb_kernel<<<wblocks(B * 512), 256, 0, stream>>>(v4, 512, 512, B, 0.64f, 32, idx);
    gemm_tiled_kernel<float><<<ggrid(B * 512, 160), 256, 0, stream>>>(L4, 256, 192, w8, b8, 160, fout);
    conv_agg32_kernel<<<B * 512 / 4, 256, 0, stream>>>(idx, v4, fout, d8, L4, 256, 192, 512, 1);
    gemm_tiled_kernel<float><<<ggrid(B * 512, 160), 256, 0, stream>>>(L4, 256, 224, w9, b9, 160, fout);
    conv_agg32_kernel<<<B * 512 / 4, 256, 0, stream>>>(idx, v4, fout, d9, L4, 256, 224, 512, 1);
    pool_fused_kernel<<<wblocks(B * 256), 256, 0, stream>>>(v4, 512, 256, B, 0.64f, L4, 256, L5, 288, 256, v5);

    // ---- Level 5 (V=256, r=1.0) ----
    qb_kernel<<<wblocks(B * 256), 256, 0, stream>>>(v5, 256, 256, B, 1.0f, 32, idx);
    gemm_tiled_kernel<float><<<ggrid(B * 256, 160), 256, 0, stream>>>(L5, 288, 256, w10, b10, 160, fout);
    conv_agg32_kernel<<<B * 256 / 4, 256, 0, stream>>>(idx, v5, fout, d10, L5, 288, 256, 256, 1);
    __hip_bfloat16* fout_bf = (__hip_bfloat16*)fout;
    gemm_tiled128_kernel<__hip_bfloat16><<<ggrid128(B * 256, 5120), 256, 0, stream>>>(L5, 288, 288, w11, b11, 5120, fout_bf);
    conv_agg_big_kernel<<<B * 256, 256, 0, stream>>>(idx, v5, fout_bf, d11, G, 256, B);

    // ---- Head ----
    gmax_kernel<<<tblocks(B * 1024), 256, 0, stream>>>(G, gm, 256, B);
    fc1_kernel<<<dim3(8, B), 256, 0, stream>>>(gm, fc1_w, fc1_b, bn_g, bn_b, bn_m, bn_v, hh);
    fc2_kernel<<<B, 256, 0, stream>>>(hh, fc2_w, fc2_b, (float*)d_out);
}

// Round 6
// 489.366 us; speedup vs baseline: 3.2801x; 1.1269x over previous
//
#include <hip/hip_runtime.h>
#include <hip/hip_bf16.h>
#include <math.h>

#define DEV __device__ __forceinline__

DEV float frn_mul(float a, float b) { return __fmul_rn(a, b); }
DEV float frn_add(float a, float b) { return __fadd_rn(a, b); }

union BFU { __hip_bfloat16 h; unsigned short u; };

// ---------------------------------------------------------------------------
// query_ball: one wave per query; K smallest-index in-range, pad with first.
// ---------------------------------------------------------------------------
__global__ void qb_kernel(const float* __restrict__ verts, int Vp, int Vq, int B,
                          float r2, int K, int* __restrict__ idx_out)
{
    int wid = (blockIdx.x * blockDim.x + threadIdx.x) >> 6;
    int lane = threadIdx.x & 63;
    int nq = B * Vq;
    if (wid >= nq) return;
    int b = wid / Vq;
    int v = wid - b * Vq;

    const float* q = verts + (size_t)(b * Vp + v) * 3;
    float qx = q[0], qy = q[1], qz = q[2];
    float qn = frn_add(frn_add(frn_mul(qx, qx), frn_mul(qy, qy)), frn_mul(qz, qz));
    const float* pts = verts + (size_t)b * Vp * 3;
    int* row = idx_out + (size_t)wid * K;

    int count = 0;
    int first = -1;
    for (int base = 0; base < Vp && count < K; base += 64) {
        int j = base + lane;
        bool in = false;
        if (j < Vp) {
            float px = pts[j * 3 + 0], py = pts[j * 3 + 1], pz = pts[j * 3 + 2];
            float pn = frn_add(frn_add(frn_mul(px, px), frn_mul(py, py)), frn_mul(pz, pz));
            float dt = frn_add(frn_add(frn_mul(qx, px), frn_mul(qy, py)), frn_mul(qz, pz));
            float d = __fsub_rn(frn_add(qn, pn), frn_mul(2.0f, dt));
            in = !(d > r2);
        }
        unsigned long long mask = __ballot(in);
        if (first < 0 && mask != 0ull)
            first = base + (int)__ffsll((long long)mask) - 1;
        int pos = count + (int)__popcll(mask & ((1ull << lane) - 1ull));
        if (in && pos < K) row[pos] = j;
        count += (int)__popcll(mask);
    }
    int cnt = count < K ? count : K;
    for (int t = cnt + lane; t < K; t += 64) row[t] = first;
}

// ---------------------------------------------------------------------------
// L1 fused: query_ball(K=32) + conv_surface. One wave per vertex; scanned
// indices stashed in LDS for the surface pass. Grid must be exactly B*V/4.
// ---------------------------------------------------------------------------
__global__ void qb_surface_kernel(const float* __restrict__ verts, int V, int B,
                                  float r2,
                                  const float* __restrict__ dirs, // (3,128)
                                  float* __restrict__ outF, int Cw,
                                  int* __restrict__ idx_out)
{
    __shared__ int rowS[4][32];
    int wid = (blockIdx.x * blockDim.x + threadIdx.x) >> 6;
    int lane = threadIdx.x & 63;
    int wql = threadIdx.x >> 6;
    int b = wid / V;
    int v = wid - b * V;

    const float* q = verts + (size_t)wid * 3;
    float qx = q[0], qy = q[1], qz = q[2];
    float qn = frn_add(frn_add(frn_mul(qx, qx), frn_mul(qy, qy)), frn_mul(qz, qz));
    const float* pts = verts + (size_t)b * V * 3;
    int* row = idx_out + (size_t)wid * 32;
    (void)v;

    int count = 0;
    int first = -1;
    for (int base = 0; base < V && count < 32; base += 64) {
        int j = base + lane;
        float px = pts[j * 3 + 0], py = pts[j * 3 + 1], pz = pts[j * 3 + 2];
        float pn = frn_add(frn_add(frn_mul(px, px), frn_mul(py, py)), frn_mul(pz, pz));
        float dt = frn_add(frn_add(frn_mul(qx, px), frn_mul(qy, py)), frn_mul(qz, pz));
        float d = __fsub_rn(frn_add(qn, pn), frn_mul(2.0f, dt));
        bool in = !(d > r2);
        unsigned long long mask = __ballot(in);
        if (first < 0 && mask != 0ull)
            first = base + (int)__ffsll((long long)mask) - 1;
        int pos = count + (int)__popcll(mask & ((1ull << lane) - 1ull));
        if (in && pos < 32) { row[pos] = j; rowS[wql][pos] = j; }
        count += (int)__popcll(mask);
    }
    int cnt = count < 32 ? count : 32;
    for (int t = cnt + lane; t < 32; t += 64) { row[t] = first; rowS[wql][t] = first; }
    __syncthreads();

    // ---- surface ----
    float dnx, dny, dnz;
    {
        int k = lane & 31;
        int nb = rowS[wql][k];
        int nbrow = b * V + nb;
        float dx = verts[(size_t)nbrow * 3 + 0] - qx;
        float dy = verts[(size_t)nbrow * 3 + 1] - qy;
        float dz = verts[(size_t)nbrow * 3 + 2] - qz;
        float nrm = sqrtf(dx * dx + dy * dy + dz * dz) + 1e-12f;
        float inv = 1.0f / nrm;
        dnx = dx * inv; dny = dy * inv; dnz = dz * inv;
    }
    int m1 = lane, m2 = lane + 64;
    float ax = dirs[m1], ay = dirs[128 + m1], az = dirs[256 + m1];
    float i1 = 1.0f / (sqrtf(ax * ax + ay * ay + az * az) + 1e-12f);
    ax *= i1; ay *= i1; az *= i1;
    float bx = dirs[m2], by = dirs[128 + m2], bz = dirs[256 + m2];
    float i2 = 1.0f / (sqrtf(bx * bx + by * by + bz * bz) + 1e-12f);
    bx *= i2; by *= i2; bz *= i2;

    float mx1 = -INFINITY, mx2 = -INFINITY;
    for (int k = 0; k < 32; ++k) {
        float ex = __shfl(dnx, k, 64);
        float ey = __shfl(dny, k, 64);
        float ez = __shfl(dnz, k, 64);
        float t1 = fmaxf(ex * ax + ey * ay + ez * az, 0.0f);
        float t2 = fmaxf(ex * bx + ey * by + ez * bz, 0.0f);
        mx1 = fmaxf(mx1, t1);
        mx2 = fmaxf(mx2, t2);
    }
    float part = mx1 + mx2;
    float tot = part + __shfl_xor(part, 32, 64);
    if (lane < 32) {
        outF[(size_t)wid * Cw + lane] = fmaxf(tot, 0.0f);
    }
}

// ---------------------------------------------------------------------------
// Tiled GEMM (64x64, 4x4 micro): small-N layer GEMMs. Proven conflict-free.
// ---------------------------------------------------------------------------
template <typename OT>
__global__ __launch_bounds__(256)
void gemm_tiled_kernel(const float* __restrict__ feat, int Cw, int cin,
                       const float* __restrict__ w, const float* __restrict__ bias,
                       int N, OT* __restrict__ fout)
{
    __shared__ float As[64][36];
    __shared__ float Bs[32][68];

    int m0 = blockIdx.x * 64;
    int n0 = blockIdx.y * 64;
    int tid = threadIdx.x;
    int tx = tid & 15, ty = tid >> 4;

    float acc[4][4];
#pragma unroll
    for (int i = 0; i < 4; ++i)
#pragma unroll
        for (int j = 0; j < 4; ++j) acc[i][j] = 0.0f;

    for (int k0 = 0; k0 < cin; k0 += 32) {
#pragma unroll
        for (int i = 0; i < 2; ++i) {
            int qq = tid + i * 256;
            int row = qq >> 3, c = qq & 7;
            float4 v = *(const float4*)&feat[(size_t)(m0 + row) * Cw + k0 + 4 * c];
            *(float4*)&As[row][4 * c] = v;
        }
#pragma unroll
        for (int i = 0; i < 2; ++i) {
            int qq = tid + i * 256;
            int kr = qq >> 4, c = qq & 15;
            int n = n0 + 4 * c;
            float4 v = make_float4(0.0f, 0.0f, 0.0f, 0.0f);
            if (n < N) v = *(const float4*)&w[(size_t)(k0 + kr) * N + n];
            *(float4*)&Bs[kr][4 * c] = v;
        }
        __syncthreads();

#pragma unroll
        for (int kt = 0; kt < 32; kt += 4) {
            float4 av4[4], bv4[4];
#pragma unroll
            for (int i = 0; i < 4; ++i) av4[i] = *(const float4*)&As[ty * 4 + i][kt];
#pragma unroll
            for (int r = 0; r < 4; ++r) bv4[r] = *(const float4*)&Bs[kt + r][tx * 4];
            const float* a = (const float*)av4;
            const float* bb = (const float*)bv4;
#pragma unroll
            for (int i = 0; i < 4; ++i)
#pragma unroll
                for (int r = 0; r < 4; ++r)
#pragma unroll
                    for (int j = 0; j < 4; ++j)
                        acc[i][j] = fmaf(a[i * 4 + r], bb[r * 4 + j], acc[i][j]);
        }
        __syncthreads();
    }

    int n = n0 + tx * 4;
    if (n < N) {
        float b0 = bias[n + 0], b1 = bias[n + 1], b2 = bias[n + 2], b3 = bias[n + 3];
#pragma unroll
        for (int i = 0; i < 4; ++i) {
            int m = m0 + ty * 4 + i;
            if constexpr (__is_same(OT, float)) {
                float4 o;
                o.x = acc[i][0] + b0;
                o.y = acc[i][1] + b1;
                o.z = acc[i][2] + b2;
                o.w = acc[i][3] + b3;
                *(float4*)&fout[(size_t)m * N + n] = o;
            } else {
                BFU t0, t1, t2, t3;
                t0.h = __float2bfloat16(acc[i][0] + b0);
                t1.h = __float2bfloat16(acc[i][1] + b1);
                t2.h = __float2bfloat16(acc[i][2] + b2);
                t3.h = __float2bfloat16(acc[i][3] + b3);
                ushort4 o;
                o.x = t0.u; o.y = t1.u; o.z = t2.u; o.w = t3.u;
                *(ushort4*)&fout[(size_t)m * N + n] = o;
            }
        }
    }
}

// ---------------------------------------------------------------------------
// 64x128-tile GEMM (4x8 micro) — conv11. Same staging patterns as 64x64
// (row-major padded, float4 writes along padded dim) → conflict-free.
// Grid (M/64, ceil(N/128)) = (16, 40) = 640 blocks for conv11.
// ---------------------------------------------------------------------------
template <typename OT>
__global__ __launch_bounds__(256)
void gemm_tiled_n128_kernel(const float* __restrict__ feat, int Cw, int cin,
                            const float* __restrict__ w, const float* __restrict__ bias,
                            int N, OT* __restrict__ fout)
{
    __shared__ float As[64][36];
    __shared__ float Bs[32][132];

    int m0 = blockIdx.x * 64;
    int n0 = blockIdx.y * 128;
    int tid = threadIdx.x;
    int tx = tid & 15, ty = tid >> 4;

    float acc[4][8];
#pragma unroll
    for (int i = 0; i < 4; ++i)
#pragma unroll
        for (int j = 0; j < 8; ++j) acc[i][j] = 0.0f;

    for (int k0 = 0; k0 < cin; k0 += 32) {
#pragma unroll
        for (int i = 0; i < 2; ++i) {
            int qq = tid + i * 256;
            int row = qq >> 3, c = qq & 7;
            float4 v = *(const float4*)&feat[(size_t)(m0 + row) * Cw + k0 + 4 * c];
            *(float4*)&As[row][4 * c] = v;
        }
#pragma unroll
        for (int i = 0; i < 4; ++i) {
            int qq = tid + i * 256;
            int kr = qq >> 5, c = qq & 31;
            int n = n0 + 4 * c;
            float4 v = make_float4(0.0f, 0.0f, 0.0f, 0.0f);
            if (n < N) v = *(const float4*)&w[(size_t)(k0 + kr) * N + n];
            *(float4*)&Bs[kr][4 * c] = v;
        }
        __syncthreads();

#pragma unroll
        for (int kt = 0; kt < 32; kt += 4) {
            float4 av4[4];
            float4 bv4[4][2];
#pragma unroll
            for (int i = 0; i < 4; ++i) av4[i] = *(const float4*)&As[ty * 4 + i][kt];
#pragma unroll
            for (int r = 0; r < 4; ++r) {
                bv4[r][0] = *(const float4*)&Bs[kt + r][tx * 4];
                bv4[r][1] = *(const float4*)&Bs[kt + r][64 + tx * 4];
            }
            const float* a = (const float*)av4;
            const float* bb = (const float*)bv4;
#pragma unroll
            for (int i = 0; i < 4; ++i)
#pragma unroll
                for (int r = 0; r < 4; ++r)
#pragma unroll
                    for (int j = 0; j < 8; ++j)
                        acc[i][j] = fmaf(a[i * 4 + r], bb[r * 8 + j], acc[i][j]);
        }
        __syncthreads();
    }

#pragma unroll
    for (int half = 0; half < 2; ++half) {
        int n = n0 + half * 64 + tx * 4;
        if (n < N) {
            float b0 = bias[n + 0], b1 = bias[n + 1], b2 = bias[n + 2], b3 = bias[n + 3];
#pragma unroll
            for (int i = 0; i < 4; ++i) {
                int m = m0 + ty * 4 + i;
                float o0 = acc[i][half * 4 + 0] + b0;
                float o1 = acc[i][half * 4 + 1] + b1;
                float o2 = acc[i][half * 4 + 2] + b2;
                float o3 = acc[i][half * 4 + 3] + b3;
                if constexpr (__is_same(OT, float)) {
                    float4 o; o.x = o0; o.y = o1; o.z = o2; o.w = o3;
                    *(float4*)&fout[(size_t)m * N + n] = o;
                } else {
                    BFU t0, t1, t2, t3;
                    t0.h = __float2bfloat16(o0);
                    t1.h = __float2bfloat16(o1);
                    t2.h = __float2bfloat16(o2);
                    t3.h = __float2bfloat16(o3);
                    ushort4 o; o.x = t0.u; o.y = t1.u; o.z = t2.u; o.w = t3.u;
                    *(ushort4*)&fout[(size_t)m * N + n] = o;
                }
            }
        }
    }
}

// ---------------------------------------------------------------------------
// conv_layer aggregation, cout=32. One wave per (b,v), XCD-swizzled.
// Grid exactly B*V/4 blocks of 256.
// ---------------------------------------------------------------------------
__global__ void conv_agg32_kernel(const int* __restrict__ idx,
                                  const float* __restrict__ verts,
                                  const float* __restrict__ fout,
                                  const float* __restrict__ dirs, // (3,128)
                                  float* __restrict__ outF, int Cw, int coff,
                                  int V, int do_relu)
{
    int blk = blockIdx.x;
    int b = (blk & 7) >> 1;
    int j = ((blk >> 3) << 1) | (blk & 1);
    int wid = b * V + j * 4 + (int)(threadIdx.x >> 6);
    int lane = threadIdx.x & 63;

    float dnx, dny, dnz;
    int nbrow;
    {
        int k = lane & 31;
        int nb = idx[(size_t)wid * 32 + k];
        nbrow = b * V + nb;
        float cx = verts[(size_t)wid * 3 + 0];
        float cy = verts[(size_t)wid * 3 + 1];
        float cz = verts[(size_t)wid * 3 + 2];
        float dx = verts[(size_t)nbrow * 3 + 0] - cx;
        float dy = verts[(size_t)nbrow * 3 + 1] - cy;
        float dz = verts[(size_t)nbrow * 3 + 2] - cz;
        float nrm = sqrtf(dx * dx + dy * dy + dz * dz) + 1e-12f;
        float inv = 1.0f / nrm;
        dnx = dx * inv; dny = dy * inv; dnz = dz * inv;
    }
    int m1 = lane, m2 = lane + 64;
    float ax = dirs[m1], ay = dirs[128 + m1], az = dirs[256 + m1];
    float i1 = 1.0f / (sqrtf(ax * ax + ay * ay + az * az) + 1e-12f);
    ax *= i1; ay *= i1; az *= i1;
    float bx = dirs[m2], by = dirs[128 + m2], bz = dirs[256 + m2];
    float i2 = 1.0f / (sqrtf(bx * bx + by * by + bz * bz) + 1e-12f);
    bx *= i2; by *= i2; bz *= i2;

    float mx1 = -INFINITY, mx2 = -INFINITY;
    for (int k = 0; k < 32; ++k) {
        float ex = __shfl(dnx, k, 64);
        float ey = __shfl(dny, k, 64);
        float ez = __shfl(dnz, k, 64);
        int nr = __shfl(nbrow, k, 64);
        const float* fr = fout + (size_t)nr * 160 + 32;
        float t1 = fmaxf(ex * ax + ey * ay + ez * az, 0.0f);
        float t2 = fmaxf(ex * bx + ey * by + ez * bz, 0.0f);
        mx1 = fmaxf(mx1, t1 * fr[m1]);
        mx2 = fmaxf(mx2, t2 * fr[m2]);
    }
    float part = mx1 + mx2;
    float tot = part + __shfl_xor(part, 32, 64);
    if (lane < 32) {
        float c = fout[(size_t)wid * 160 + lane];
        float val = c + tot;
        if (do_relu) val = fmaxf(val, 0.0f);
        outF[(size_t)wid * Cw + coff + lane] = val;
    }
}

// ---------------------------------------------------------------------------
// conv11 aggregation: cout=1024. One block per (b,v), XCD-swizzled. bf16 fout.
// ---------------------------------------------------------------------------
__global__ void conv_agg_big_kernel(const int* __restrict__ idx,
                                    const float* __restrict__ verts,
                                    const __hip_bfloat16* __restrict__ fout,
                                    const float* __restrict__ dirs,
                                    float* __restrict__ G,
                                    int V, int B)
{
    __shared__ float dnS[32][3];
    __shared__ int nbS[32];
    int blk = blockIdx.x;
    int b = (blk & 7) >> 1;
    int v = ((blk >> 3) << 1) | (blk & 1);
    int row = b * V + v;
    int tid = threadIdx.x;

    if (tid < 32) {
        int nb = idx[(size_t)row * 32 + tid];
        int nbrow = b * V + nb;
        float cx = verts[(size_t)row * 3 + 0];
        float cy = verts[(size_t)row * 3 + 1];
        float cz = verts[(size_t)row * 3 + 2];
        float dx = verts[(size_t)nbrow * 3 + 0] - cx;
        float dy = verts[(size_t)nbrow * 3 + 1] - cy;
        float dz = verts[(size_t)nbrow * 3 + 2] - cz;
        float nrm = sqrtf(dx * dx + dy * dy + dz * dz) + 1e-12f;
        float inv = 1.0f / nrm;
        dnS[tid][0] = dx * inv; dnS[tid][1] = dy * inv; dnS[tid][2] = dz * inv;
        nbS[tid] = nbrow;
    }
    __syncthreads();

    float sdx[16], sdy[16], sdz[16], mx[16];
    for (int p = 0; p < 16; ++p) {
        int pair = p * 256 + tid;
        float ax = dirs[pair], ay = dirs[4096 + pair], az = dirs[8192 + pair];
        float inv = 1.0f / (sqrtf(ax * ax + ay * ay + az * az) + 1e-12f);
        sdx[p] = ax * inv; sdy[p] = ay * inv; sdz[p] = az * inv;
        mx[p] = -INFINITY;
    }
    for (int k = 0; k < 32; ++k) {
        float ex = dnS[k][0], ey = dnS[k][1], ez = dnS[k][2];
        const __hip_bfloat16* fr = fout + (size_t)nbS[k] * 5120 + 1024;
        for (int p = 0; p < 16; ++p) {
            float th = fmaxf(ex * sdx[p] + ey * sdy[p] + ez * sdz[p], 0.0f);
            float s = __bfloat162float(fr[p * 256 + tid]);
            mx[p] = fmaxf(mx[p], th * s);
        }
    }
    for (int q = 0; q < 4; ++q) {
        float val = ((mx[q] + mx[4 + q]) + mx[8 + q]) + mx[12 + q];
        int oo = q * 256 + tid;
        float c = __bfloat162float(fout[(size_t)row * 5120 + oo]);
        G[(size_t)row * 1024 + oo] = c + val;
    }
}

// ---------------------------------------------------------------------------
// Pool v2: reuses conv idx (pool idx == first 4 of conv idx: same radius,
// query prefix, same padding semantics). Pure gather + verts copy.
// ---------------------------------------------------------------------------
__global__ void pool_fused_kernel(const int* __restrict__ idx_conv,
                                  const float* __restrict__ verts, int Vp, int Vh, int B,
                                  const float* __restrict__ Fin, int CwIn,
                                  float* __restrict__ Fout, int CwOut, int C,
                                  float* __restrict__ vout)
{
    int wid = (blockIdx.x * blockDim.x + threadIdx.x) >> 6;
    int lane = threadIdx.x & 63;
    int nq = B * Vh;
    if (wid >= nq) return;
    int b = wid / Vh;
    int v = wid - b * Vh;
    int rowc = b * Vp + v;

    int idv = 0;
    if (lane < 4) idv = idx_conv[(size_t)rowc * 32 + lane];
    int i0 = __shfl(idv, 0, 64);
    int i1 = __shfl(idv, 1, 64);
    int i2 = __shfl(idv, 2, 64);
    int i3 = __shfl(idv, 3, 64);

    const float* r0 = Fin + (size_t)(b * Vp + i0) * CwIn;
    const float* r1 = Fin + (size_t)(b * Vp + i1) * CwIn;
    const float* r2p = Fin + (size_t)(b * Vp + i2) * CwIn;
    const float* r3 = Fin + (size_t)(b * Vp + i3) * CwIn;
    for (int c = lane; c < C; c += 64) {
        float m = fmaxf(fmaxf(r0[c], r1[c]), fmaxf(r2p[c], r3[c]));
        Fout[(size_t)wid * CwOut + c] = m;
    }
    if (lane < 3) vout[(size_t)wid * 3 + lane] = verts[(size_t)rowc * 3 + lane];
}

// ---------------------------------------------------------------------------
// Head
// ---------------------------------------------------------------------------
// gmax over V=256 rows; grid 64 blocks: b = blk>>4, c0 = (blk&15)*64.
__global__ void gmax_kernel(const float* __restrict__ G, float* __restrict__ gm,
                            int V)
{
    __shared__ float red[4][64];
    int b = blockIdx.x >> 4;
    int c0 = (blockIdx.x & 15) * 64;
    int t = threadIdx.x;
    int c = c0 + (t & 63);
    int vg = t >> 6;
    float m = -INFINITY;
    for (int v = vg * 64; v < (vg + 1) * 64; ++v)
        m = fmaxf(m, G[((size_t)b * V + v) * 1024 + c]);
    red[vg][t & 63] = m;
    __syncthreads();
    if (t < 64) {
        float r = fmaxf(fmaxf(red[0][t], red[1][t]), fmaxf(red[2][t], red[3][t]));
        gm[b * 1024 + c0 + t] = r;
    }
}

// fc1 split: grid (8, B). Block 256 = 32 j x 8 k-chunks of 128.
__global__ __launch_bounds__(256)
void fc1_kernel(const float* __restrict__ gm, const float* __restrict__ w1,
                const float* __restrict__ b1_,
                const float* __restrict__ bn_g, const float* __restrict__ bn_b,
                const float* __restrict__ bn_m, const float* __restrict__ bn_v,
                float* __restrict__ h)
{
    __shared__ float gs[1024];
    __shared__ float red[8][32];
    int b = blockIdx.y;
    int j0 = blockIdx.x * 32;
    int t = threadIdx.x;
    for (int i = t; i < 1024; i += 256) gs[i] = gm[b * 1024 + i];
    __syncthreads();
    int jj = t & 31, kk = t >> 5;
    int j = j0 + jj;
    const float* wp = w1 + (size_t)(kk * 128) * 256 + j;
    float acc = 0.0f;
#pragma unroll 8
    for (int k = 0; k < 128; ++k)
        acc = fmaf(gs[kk * 128 + k], wp[(size_t)k * 256], acc);
    red[kk][jj] = acc;
    __syncthreads();
    if (t < 32) {
        float s = 0.0f;
#pragma unroll
        for (int q = 0; q < 8; ++q) s += red[q][t];
        int jw = j0 + t;
        s += b1_[jw];
        s = (s - bn_m[jw]) / sqrtf(bn_v[jw] + 1e-5f) * bn_g[jw] + bn_b[jw];
        h[b * 256 + jw] = fmaxf(s, 0.0f);
    }
}

__global__ void fc2_kernel(const float* __restrict__ h, const float* __restrict__ w2,
                           const float* __restrict__ b2_, float* __restrict__ out)
{
    __shared__ float hs[256];
    int b = blockIdx.x;
    int t = threadIdx.x;
    hs[t] = h[b * 256 + t];
    __syncthreads();
    if (t < 40) {
        float acc = 0.0f;
#pragma unroll 8
        for (int k = 0; k < 256; ++k) acc = fmaf(hs[k], w2[(size_t)k * 40 + t], acc);
        out[b * 40 + t] = acc + b2_[t];
    }
}

// ---------------------------------------------------------------------------
static inline int wblocks(int waves) { return (waves + 3) / 4; }
static inline dim3 ggrid(int M, int N) { return dim3(M / 64, (N + 63) / 64); }
static inline dim3 ggridn128(int M, int N) { return dim3(M / 64, (N + 127) / 128); }

extern "C" void kernel_launch(void* const* d_in, const int* in_sizes, int n_in,
                              void* d_out, int out_size, void* d_ws, size_t ws_size,
                              hipStream_t stream)
{
    const int B = 4;
    const float* verts1 = (const float*)d_in[0];
    const float* surf_dirs = (const float*)d_in[1];
    const float* w1 = (const float*)d_in[2];
    const float* b1 = (const float*)d_in[3];
    const float* d1 = (const float*)d_in[4];
    const float* w3 = (const float*)d_in[5];
    const float* b3 = (const float*)d_in[6];
    const float* d3 = (const float*)d_in[7];
    const float* w4 = (const float*)d_in[8];
    const float* b4 = (const float*)d_in[9];
    const float* d4 = (const float*)d_in[10];
    const float* w6 = (const float*)d_in[11];
    const float* b6 = (const float*)d_in[12];
    const float* d6 = (const float*)d_in[13];
    const float* w7 = (const float*)d_in[14];
    const float* b7 = (const float*)d_in[15];
    const float* d7 = (const float*)d_in[16];
    const float* w8 = (const float*)d_in[17];
    const float* b8 = (const float*)d_in[18];
    const float* d8 = (const float*)d_in[19];
    const float* w9 = (const float*)d_in[20];
    const float* b9 = (const float*)d_in[21];
    const float* d9 = (const float*)d_in[22];
    const float* w10 = (const float*)d_in[23];
    const float* b10 = (const float*)d_in[24];
    const float* d10 = (const float*)d_in[25];
    const float* w11 = (const float*)d_in[26];
    const float* b11 = (const float*)d_in[27];
    const float* d11 = (const float*)d_in[28];
    const float* fc1_w = (const float*)d_in[29];
    const float* fc1_b = (const float*)d_in[30];
    const float* bn_g = (const float*)d_in[31];
    const float* bn_b = (const float*)d_in[32];
    const float* bn_m = (const float*)d_in[33];
    const float* bn_v = (const float*)d_in[34];
    const float* fc2_w = (const float*)d_in[35];
    const float* fc2_b = (const float*)d_in[36];
    (void)in_sizes; (void)n_in; (void)out_size; (void)ws_size;

    float* ws = (float*)d_ws;
    size_t off = 0;
    auto alloc = [&](size_t n) { float* p = ws + off; off += n; return p; };
    float* fout = alloc(4 * 256 * 5120);
    int* idx = (int*)alloc(4 * 4096 * 32);
    float* F1 = alloc(4 * 4096 * 64);
    float* L2 = alloc(4 * 2048 * 128);
    float* L3 = alloc(4 * 1024 * 192);
    float* L4 = alloc(4 * 512 * 256);
    float* L5 = alloc(4 * 256 * 288);
    float* G = alloc(4 * 256 * 1024);
    float* v2 = alloc(4 * 2048 * 3);
    float* v3 = alloc(4 * 1024 * 3);
    float* v4 = alloc(4 * 512 * 3);
    float* v5 = alloc(4 * 256 * 3);
    float* gm = alloc(4 * 1024);
    float* hh = alloc(4 * 256);

    // ---- Level 1 (V=4096, r=0.2) ----
    qb_surface_kernel<<<wblocks(B * 4096), 256, 0, stream>>>(verts1, 4096, B, 0.04f, surf_dirs, F1, 64, idx);
    gemm_tiled_kernel<float><<<ggrid(B * 4096, 160), 256, 0, stream>>>(F1, 64, 32, w1, b1, 160, fout);
    conv_agg32_kernel<<<B * 4096 / 4, 256, 0, stream>>>(idx, verts1, fout, d1, F1, 64, 32, 4096, 1);
    pool_fused_kernel<<<wblocks(B * 2048), 256, 0, stream>>>(idx, verts1, 4096, 2048, B, F1, 64, L2, 128, 64, v2);

    // ---- Level 2 (V=2048, r=0.4) ----
    qb_kernel<<<wblocks(B * 2048), 256, 0, stream>>>(v2, 2048, 2048, B, 0.16f, 32, idx);
    gemm_tiled_kernel<float><<<ggrid(B * 2048, 160), 256, 0, stream>>>(L2, 128, 64, w3, b3, 160, fout);
    conv_agg32_kernel<<<B * 2048 / 4, 256, 0, stream>>>(idx, v2, fout, d3, L2, 128, 64, 2048, 1);
    gemm_tiled_kernel<float><<<ggrid(B * 2048, 160), 256, 0, stream>>>(L2, 128, 96, w4, b4, 160, fout);
    conv_agg32_kernel<<<B * 2048 / 4, 256, 0, stream>>>(idx, v2, fout, d4, L2, 128, 96, 2048, 1);
    pool_fused_kernel<<<wblocks(B * 1024), 256, 0, stream>>>(idx, v2, 2048, 1024, B, L2, 128, L3, 192, 128, v3);

    // ---- Level 3 (V=1024, r=0.6) ----
    qb_kernel<<<wblocks(B * 1024), 256, 0, stream>>>(v3, 1024, 1024, B, 0.36f, 32, idx);
    gemm_tiled_kernel<float><<<ggrid(B * 1024, 160), 256, 0, stream>>>(L3, 192, 128, w6, b6, 160, fout);
    conv_agg32_kernel<<<B * 1024 / 4, 256, 0, stream>>>(idx, v3, fout, d6, L3, 192, 128, 1024, 1);
    gemm_tiled_kernel<float><<<ggrid(B * 1024, 160), 256, 0, stream>>>(L3, 192, 160, w7, b7, 160, fout);
    conv_agg32_kernel<<<B * 1024 / 4, 256, 0, stream>>>(idx, v3, fout, d7, L3, 192, 160, 1024, 1);
    pool_fused_kernel<<<wblocks(B * 512), 256, 0, stream>>>(idx, v3, 1024, 512, B, L3, 192, L4, 256, 192, v4);

    // ---- Level 4 (V=512, r=0.8) ----
    qb_kernel<<<wblocks(B * 512), 256, 0, stream>>>(v4, 512, 512, B, 0.64f, 32, idx);
    gemm_tiled_kernel<float><<<ggrid(B * 512, 160), 256, 0, stream>>>(L4, 256, 192, w8, b8, 160, fout);
    conv_agg32_kernel<<<B * 512 / 4, 256, 0, stream>>>(idx, v4, fout, d8, L4, 256, 192, 512, 1);
    gemm_tiled_kernel<float><<<ggrid(B * 512, 160), 256, 0, stream>>>(L4, 256, 224, w9, b9, 160, fout);
    conv_agg32_kernel<<<B * 512 / 4, 256, 0, stream>>>(idx, v4, fout, d9, L4, 256, 224, 512, 1);
    pool_fused_kernel<<<wblocks(B * 256), 256, 0, stream>>>(idx, v4, 512, 256, B, L4, 256, L5, 288, 256, v5);

    // ---- Level 5 (V=256, r=1.0) ----
    qb_kernel<<<wblocks(B * 256), 256, 0, stream>>>(v5, 256, 256, B, 1.0f, 32, idx);
    gemm_tiled_kernel<float><<<ggrid(B * 256, 160), 256, 0, stream>>>(L5, 288, 256, w10, b10, 160, fout);
    conv_agg32_kernel<<<B * 256 / 4, 256, 0, stream>>>(idx, v5, fout, d10, L5, 288, 256, 256, 1);
    __hip_bfloat16* fout_bf = (__hip_bfloat16*)fout;
    gemm_tiled_n128_kernel<__hip_bfloat16><<<ggridn128(B * 256, 5120), 256, 0, stream>>>(L5, 288, 288, w11, b11, 5120, fout_bf);
    conv_agg_big_kernel<<<B * 256, 256, 0, stream>>>(idx, v5, fout_bf, d11, G, 256, B);

    // ---- Head ----
    gmax_kernel<<<64, 256, 0, stream>>>(G, gm, 256);
    fc1_kernel<<<dim3(8, B), 256, 0, stream>>>(gm, fc1_w, fc1_b, bn_g, bn_b, bn_m, bn_v, hh);
    fc2_kernel<<<B, 256, 0, stream>>>(hh, fc2_w, fc2_b, (float*)d_out);
}

// Round 7
// 466.352 us; speedup vs baseline: 3.4420x; 1.0494x over previous
//
#include <hip/hip_runtime.h>
#include <hip/hip_bf16.h>
#include <math.h>

#define DEV __device__ __forceinline__

DEV float frn_mul(float a, float b) { return __fmul_rn(a, b); }
DEV float frn_add(float a, float b) { return __fadd_rn(a, b); }

union BFU { __hip_bfloat16 h; unsigned short u; };

typedef __attribute__((ext_vector_type(8))) short short8v;  // 8 bf16 (4 VGPRs)
typedef __attribute__((ext_vector_type(4))) float f32x4;

// ---------------------------------------------------------------------------
// query_ball: one wave per query; K smallest-index in-range, pad with first.
// ---------------------------------------------------------------------------
__global__ void qb_kernel(const float* __restrict__ verts, int Vp, int Vq, int B,
                          float r2, int K, int* __restrict__ idx_out)
{
    int wid = (blockIdx.x * blockDim.x + threadIdx.x) >> 6;
    int lane = threadIdx.x & 63;
    int nq = B * Vq;
    if (wid >= nq) return;
    int b = wid / Vq;
    int v = wid - b * Vq;

    const float* q = verts + (size_t)(b * Vp + v) * 3;
    float qx = q[0], qy = q[1], qz = q[2];
    float qn = frn_add(frn_add(frn_mul(qx, qx), frn_mul(qy, qy)), frn_mul(qz, qz));
    const float* pts = verts + (size_t)b * Vp * 3;
    int* row = idx_out + (size_t)wid * K;

    int count = 0;
    int first = -1;
    for (int base = 0; base < Vp && count < K; base += 64) {
        int j = base + lane;
        bool in = false;
        if (j < Vp) {
            float px = pts[j * 3 + 0], py = pts[j * 3 + 1], pz = pts[j * 3 + 2];
            float pn = frn_add(frn_add(frn_mul(px, px), frn_mul(py, py)), frn_mul(pz, pz));
            float dt = frn_add(frn_add(frn_mul(qx, px), frn_mul(qy, py)), frn_mul(qz, pz));
            float d = __fsub_rn(frn_add(qn, pn), frn_mul(2.0f, dt));
            in = !(d > r2);
        }
        unsigned long long mask = __ballot(in);
        if (first < 0 && mask != 0ull)
            first = base + (int)__ffsll((long long)mask) - 1;
        int pos = count + (int)__popcll(mask & ((1ull << lane) - 1ull));
        if (in && pos < K) row[pos] = j;
        count += (int)__popcll(mask);
    }
    int cnt = count < K ? count : K;
    for (int t = cnt + lane; t < K; t += 64) row[t] = first;
}

// ---------------------------------------------------------------------------
// L1 fused: query_ball(K=32) + conv_surface. One wave per vertex.
// ---------------------------------------------------------------------------
__global__ void qb_surface_kernel(const float* __restrict__ verts, int V, int B,
                                  float r2,
                                  const float* __restrict__ dirs, // (3,128)
                                  float* __restrict__ outF, int Cw,
                                  int* __restrict__ idx_out)
{
    __shared__ int rowS[4][32];
    int wid = (blockIdx.x * blockDim.x + threadIdx.x) >> 6;
    int lane = threadIdx.x & 63;
    int wql = threadIdx.x >> 6;
    int b = wid / V;

    const float* q = verts + (size_t)wid * 3;
    float qx = q[0], qy = q[1], qz = q[2];
    float qn = frn_add(frn_add(frn_mul(qx, qx), frn_mul(qy, qy)), frn_mul(qz, qz));
    const float* pts = verts + (size_t)b * V * 3;
    int* row = idx_out + (size_t)wid * 32;

    int count = 0;
    int first = -1;
    for (int base = 0; base < V && count < 32; base += 64) {
        int j = base + lane;
        float px = pts[j * 3 + 0], py = pts[j * 3 + 1], pz = pts[j * 3 + 2];
        float pn = frn_add(frn_add(frn_mul(px, px), frn_mul(py, py)), frn_mul(pz, pz));
        float dt = frn_add(frn_add(frn_mul(qx, px), frn_mul(qy, py)), frn_mul(qz, pz));
        float d = __fsub_rn(frn_add(qn, pn), frn_mul(2.0f, dt));
        bool in = !(d > r2);
        unsigned long long mask = __ballot(in);
        if (first < 0 && mask != 0ull)
            first = base + (int)__ffsll((long long)mask) - 1;
        int pos = count + (int)__popcll(mask & ((1ull << lane) - 1ull));
        if (in && pos < 32) { row[pos] = j; rowS[wql][pos] = j; }
        count += (int)__popcll(mask);
    }
    int cnt = count < 32 ? count : 32;
    for (int t = cnt + lane; t < 32; t += 64) { row[t] = first; rowS[wql][t] = first; }
    __syncthreads();

    float dnx, dny, dnz;
    {
        int k = lane & 31;
        int nb = rowS[wql][k];
        int nbrow = b * V + nb;
        float dx = verts[(size_t)nbrow * 3 + 0] - qx;
        float dy = verts[(size_t)nbrow * 3 + 1] - qy;
        float dz = verts[(size_t)nbrow * 3 + 2] - qz;
        float nrm = sqrtf(dx * dx + dy * dy + dz * dz) + 1e-12f;
        float inv = 1.0f / nrm;
        dnx = dx * inv; dny = dy * inv; dnz = dz * inv;
    }
    int m1 = lane, m2 = lane + 64;
    float ax = dirs[m1], ay = dirs[128 + m1], az = dirs[256 + m1];
    float i1 = 1.0f / (sqrtf(ax * ax + ay * ay + az * az) + 1e-12f);
    ax *= i1; ay *= i1; az *= i1;
    float bx = dirs[m2], by = dirs[128 + m2], bz = dirs[256 + m2];
    float i2 = 1.0f / (sqrtf(bx * bx + by * by + bz * bz) + 1e-12f);
    bx *= i2; by *= i2; bz *= i2;

    float mx1 = -INFINITY, mx2 = -INFINITY;
    for (int k = 0; k < 32; ++k) {
        float ex = __shfl(dnx, k, 64);
        float ey = __shfl(dny, k, 64);
        float ez = __shfl(dnz, k, 64);
        float t1 = fmaxf(ex * ax + ey * ay + ez * az, 0.0f);
        float t2 = fmaxf(ex * bx + ey * by + ez * bz, 0.0f);
        mx1 = fmaxf(mx1, t1);
        mx2 = fmaxf(mx2, t2);
    }
    float part = mx1 + mx2;
    float tot = part + __shfl_xor(part, 32, 64);
    if (lane < 32) {
        outF[(size_t)wid * Cw + lane] = fmaxf(tot, 0.0f);
    }
}

// ---------------------------------------------------------------------------
// Tiled GEMM (64x64, 4x4 micro): small-N layer GEMMs (fp32, proven).
// ---------------------------------------------------------------------------
template <typename OT>
__global__ __launch_bounds__(256)
void gemm_tiled_kernel(const float* __restrict__ feat, int Cw, int cin,
                       const float* __restrict__ w, const float* __restrict__ bias,
                       int N, OT* __restrict__ fout)
{
    __shared__ float As[64][36];
    __shared__ float Bs[32][68];

    int m0 = blockIdx.x * 64;
    int n0 = blockIdx.y * 64;
    int tid = threadIdx.x;
    int tx = tid & 15, ty = tid >> 4;

    float acc[4][4];
#pragma unroll
    for (int i = 0; i < 4; ++i)
#pragma unroll
        for (int j = 0; j < 4; ++j) acc[i][j] = 0.0f;

    for (int k0 = 0; k0 < cin; k0 += 32) {
#pragma unroll
        for (int i = 0; i < 2; ++i) {
            int qq = tid + i * 256;
            int row = qq >> 3, c = qq & 7;
            float4 v = *(const float4*)&feat[(size_t)(m0 + row) * Cw + k0 + 4 * c];
            *(float4*)&As[row][4 * c] = v;
        }
#pragma unroll
        for (int i = 0; i < 2; ++i) {
            int qq = tid + i * 256;
            int kr = qq >> 4, c = qq & 15;
            int n = n0 + 4 * c;
            float4 v = make_float4(0.0f, 0.0f, 0.0f, 0.0f);
            if (n < N) v = *(const float4*)&w[(size_t)(k0 + kr) * N + n];
            *(float4*)&Bs[kr][4 * c] = v;
        }
        __syncthreads();

#pragma unroll
        for (int kt = 0; kt < 32; kt += 4) {
            float4 av4[4], bv4[4];
#pragma unroll
            for (int i = 0; i < 4; ++i) av4[i] = *(const float4*)&As[ty * 4 + i][kt];
#pragma unroll
            for (int r = 0; r < 4; ++r) bv4[r] = *(const float4*)&Bs[kt + r][tx * 4];
            const float* a = (const float*)av4;
            const float* bb = (const float*)bv4;
#pragma unroll
            for (int i = 0; i < 4; ++i)
#pragma unroll
                for (int r = 0; r < 4; ++r)
#pragma unroll
                    for (int j = 0; j < 4; ++j)
                        acc[i][j] = fmaf(a[i * 4 + r], bb[r * 4 + j], acc[i][j]);
        }
        __syncthreads();
    }

    int n = n0 + tx * 4;
    if (n < N) {
        float b0 = bias[n + 0], b1 = bias[n + 1], b2 = bias[n + 2], b3 = bias[n + 3];
#pragma unroll
        for (int i = 0; i < 4; ++i) {
            int m = m0 + ty * 4 + i;
            if constexpr (__is_same(OT, float)) {
                float4 o;
                o.x = acc[i][0] + b0;
                o.y = acc[i][1] + b1;
                o.z = acc[i][2] + b2;
                o.w = acc[i][3] + b3;
                *(float4*)&fout[(size_t)m * N + n] = o;
            } else {
                BFU t0, t1, t2, t3;
                t0.h = __float2bfloat16(acc[i][0] + b0);
                t1.h = __float2bfloat16(acc[i][1] + b1);
                t2.h = __float2bfloat16(acc[i][2] + b2);
                t3.h = __float2bfloat16(acc[i][3] + b3);
                ushort4 o;
                o.x = t0.u; o.y = t1.u; o.z = t2.u; o.w = t3.u;
                *(ushort4*)&fout[(size_t)m * N + n] = o;
            }
        }
    }
}

// ---------------------------------------------------------------------------
// Prep for conv11 MFMA: cast fp32 -> bf16 (row-major copy).
// ---------------------------------------------------------------------------
__global__ void cast_bf16_kernel(const float* __restrict__ src,
                                 unsigned short* __restrict__ dst, int n8)
{
    int t = blockIdx.x * blockDim.x + threadIdx.x;
    if (t >= n8) return;
    float4 v0 = *(const float4*)&src[(size_t)t * 8];
    float4 v1 = *(const float4*)&src[(size_t)t * 8 + 4];
    BFU a;
    ushort4 o0, o1;
    a.h = __float2bfloat16(v0.x); o0.x = a.u;
    a.h = __float2bfloat16(v0.y); o0.y = a.u;
    a.h = __float2bfloat16(v0.z); o0.z = a.u;
    a.h = __float2bfloat16(v0.w); o0.w = a.u;
    a.h = __float2bfloat16(v1.x); o1.x = a.u;
    a.h = __float2bfloat16(v1.y); o1.y = a.u;
    a.h = __float2bfloat16(v1.z); o1.z = a.u;
    a.h = __float2bfloat16(v1.w); o1.w = a.u;
    *(ushort4*)&dst[(size_t)t * 8] = o0;
    *(ushort4*)&dst[(size_t)t * 8 + 4] = o1;
}

// w11 [288][5120] fp32 -> wt [5120][288] bf16 (transpose+cast; coalesced reads)
__global__ void castT_bf16_kernel(const float* __restrict__ w,
                                  unsigned short* __restrict__ wt)
{
    int t = blockIdx.x * blockDim.x + threadIdx.x; // < 5120*36
    if (t >= 5120 * 36) return;
    int kc = t / 5120;
    int n = t - kc * 5120;
    BFU a;
    ushort4 o0, o1;
    a.h = __float2bfloat16(w[(size_t)(kc * 8 + 0) * 5120 + n]); o0.x = a.u;
    a.h = __float2bfloat16(w[(size_t)(kc * 8 + 1) * 5120 + n]); o0.y = a.u;
    a.h = __float2bfloat16(w[(size_t)(kc * 8 + 2) * 5120 + n]); o0.z = a.u;
    a.h = __float2bfloat16(w[(size_t)(kc * 8 + 3) * 5120 + n]); o0.w = a.u;
    a.h = __float2bfloat16(w[(size_t)(kc * 8 + 4) * 5120 + n]); o1.x = a.u;
    a.h = __float2bfloat16(w[(size_t)(kc * 8 + 5) * 5120 + n]); o1.y = a.u;
    a.h = __float2bfloat16(w[(size_t)(kc * 8 + 6) * 5120 + n]); o1.z = a.u;
    a.h = __float2bfloat16(w[(size_t)(kc * 8 + 7) * 5120 + n]); o1.w = a.u;
    *(ushort4*)&wt[(size_t)n * 288 + kc * 8] = o0;
    *(ushort4*)&wt[(size_t)n * 288 + kc * 8 + 4] = o1;
}

// ---------------------------------------------------------------------------
// conv11 GEMM via bf16 MFMA. Fixed M=1024, K=288, N=5120.
// 128x128 tile, 4 waves (2x2), each wave 64x64 = 4x4 frags of 16x16x32.
// A [m][k] bf16, B^T [n][k] bf16; LDS rows padded to 40 ushorts (80B:
// 16B-aligned frag reads, <=2-way bank aliasing).
// C/D mapping (m89-verified): col=lane&15, row=(lane>>4)*4+reg.
// ---------------------------------------------------------------------------
__global__ __launch_bounds__(256)
void gemm_mfma_conv11(const unsigned short* __restrict__ Abf,
                      const unsigned short* __restrict__ WTbf,
                      const float* __restrict__ bias,
                      __hip_bfloat16* __restrict__ fout)
{
    __shared__ unsigned short As[128][40];
    __shared__ unsigned short Bs[128][40];
    const int K = 288, N = 5120;
    int m0 = blockIdx.x * 128;
    int n0 = blockIdx.y * 128;
    int tid = threadIdx.x;
    int lane = tid & 63;
    int wave = tid >> 6;
    int wm = wave & 1, wn = wave >> 1;
    int l15 = lane & 15, l4 = lane >> 4;

    f32x4 acc[4][4];
#pragma unroll
    for (int mi = 0; mi < 4; ++mi)
#pragma unroll
        for (int ni = 0; ni < 4; ++ni) acc[mi][ni] = (f32x4){0.f, 0.f, 0.f, 0.f};

    for (int k0 = 0; k0 < K; k0 += 32) {
#pragma unroll
        for (int i = 0; i < 2; ++i) {
            int c = tid + i * 256;          // 0..511
            int row = c >> 2, qq = c & 3;   // row 0..127, 16B chunk 0..3
            *(uint4*)&As[row][qq * 8] = *(const uint4*)&Abf[(size_t)(m0 + row) * K + k0 + qq * 8];
            *(uint4*)&Bs[row][qq * 8] = *(const uint4*)&WTbf[(size_t)(n0 + row) * K + k0 + qq * 8];
        }
        __syncthreads();

        short8v af[4], bfv[4];
#pragma unroll
        for (int mi = 0; mi < 4; ++mi)
            af[mi] = *(const short8v*)&As[wm * 64 + mi * 16 + l15][l4 * 8];
#pragma unroll
        for (int ni = 0; ni < 4; ++ni)
            bfv[ni] = *(const short8v*)&Bs[wn * 64 + ni * 16 + l15][l4 * 8];
#pragma unroll
        for (int mi = 0; mi < 4; ++mi)
#pragma unroll
            for (int ni = 0; ni < 4; ++ni)
                acc[mi][ni] = __builtin_amdgcn_mfma_f32_16x16x32_bf16(af[mi], bfv[ni], acc[mi][ni], 0, 0, 0);
        __syncthreads();
    }

#pragma unroll
    for (int ni = 0; ni < 4; ++ni) {
        int col = n0 + wn * 64 + ni * 16 + l15;
        float bv = bias[col];
#pragma unroll
        for (int mi = 0; mi < 4; ++mi) {
            int rbase = m0 + wm * 64 + mi * 16 + l4 * 4;
#pragma unroll
            for (int j = 0; j < 4; ++j) {
                BFU u;
                u.h = __float2bfloat16(acc[mi][ni][j] + bv);
                *(unsigned short*)&fout[(size_t)(rbase + j) * N + col] = u.u;
            }
        }
    }
}

// ---------------------------------------------------------------------------
// conv_layer aggregation, cout=32. One wave per (b,v), XCD-swizzled.
// ---------------------------------------------------------------------------
__global__ void conv_agg32_kernel(const int* __restrict__ idx,
                                  const float* __restrict__ verts,
                                  const float* __restrict__ fout,
                                  const float* __restrict__ dirs, // (3,128)
                                  float* __restrict__ outF, int Cw, int coff,
                                  int V, int do_relu)
{
    int blk = blockIdx.x;
    int b = (blk & 7) >> 1;
    int j = ((blk >> 3) << 1) | (blk & 1);
    int wid = b * V + j * 4 + (int)(threadIdx.x >> 6);
    int lane = threadIdx.x & 63;

    float dnx, dny, dnz;
    int nbrow;
    {
        int k = lane & 31;
        int nb = idx[(size_t)wid * 32 + k];
        nbrow = b * V + nb;
        float cx = verts[(size_t)wid * 3 + 0];
        float cy = verts[(size_t)wid * 3 + 1];
        float cz = verts[(size_t)wid * 3 + 2];
        float dx = verts[(size_t)nbrow * 3 + 0] - cx;
        float dy = verts[(size_t)nbrow * 3 + 1] - cy;
        float dz = verts[(size_t)nbrow * 3 + 2] - cz;
        float nrm = sqrtf(dx * dx + dy * dy + dz * dz) + 1e-12f;
        float inv = 1.0f / nrm;
        dnx = dx * inv; dny = dy * inv; dnz = dz * inv;
    }
    int m1 = lane, m2 = lane + 64;
    float ax = dirs[m1], ay = dirs[128 + m1], az = dirs[256 + m1];
    float i1 = 1.0f / (sqrtf(ax * ax + ay * ay + az * az) + 1e-12f);
    ax *= i1; ay *= i1; az *= i1;
    float bx = dirs[m2], by = dirs[128 + m2], bz = dirs[256 + m2];
    float i2 = 1.0f / (sqrtf(bx * bx + by * by + bz * bz) + 1e-12f);
    bx *= i2; by *= i2; bz *= i2;

    float mx1 = -INFINITY, mx2 = -INFINITY;
    for (int k = 0; k < 32; ++k) {
        float ex = __shfl(dnx, k, 64);
        float ey = __shfl(dny, k, 64);
        float ez = __shfl(dnz, k, 64);
        int nr = __shfl(nbrow, k, 64);
        const float* fr = fout + (size_t)nr * 160 + 32;
        float t1 = fmaxf(ex * ax + ey * ay + ez * az, 0.0f);
        float t2 = fmaxf(ex * bx + ey * by + ez * bz, 0.0f);
        mx1 = fmaxf(mx1, t1 * fr[m1]);
        mx2 = fmaxf(mx2, t2 * fr[m2]);
    }
    float part = mx1 + mx2;
    float tot = part + __shfl_xor(part, 32, 64);
    if (lane < 32) {
        float c = fout[(size_t)wid * 160 + lane];
        float val = c + tot;
        if (do_relu) val = fmaxf(val, 0.0f);
        outF[(size_t)wid * Cw + coff + lane] = val;
    }
}

// ---------------------------------------------------------------------------
// conv11 aggregation: cout=1024. One block per (b,v), XCD-swizzled. bf16 fout.
// ---------------------------------------------------------------------------
__global__ void conv_agg_big_kernel(const int* __restrict__ idx,
                                    const float* __restrict__ verts,
                                    const __hip_bfloat16* __restrict__ fout,
                                    const float* __restrict__ dirs,
                                    float* __restrict__ G,
                                    int V, int B)
{
    __shared__ float dnS[32][3];
    __shared__ int nbS[32];
    int blk = blockIdx.x;
    int b = (blk & 7) >> 1;
    int v = ((blk >> 3) << 1) | (blk & 1);
    int row = b * V + v;
    int tid = threadIdx.x;

    if (tid < 32) {
        int nb = idx[(size_t)row * 32 + tid];
        int nbrow = b * V + nb;
        float cx = verts[(size_t)row * 3 + 0];
        float cy = verts[(size_t)row * 3 + 1];
        float cz = verts[(size_t)row * 3 + 2];
        float dx = verts[(size_t)nbrow * 3 + 0] - cx;
        float dy = verts[(size_t)nbrow * 3 + 1] - cy;
        float dz = verts[(size_t)nbrow * 3 + 2] - cz;
        float nrm = sqrtf(dx * dx + dy * dy + dz * dz) + 1e-12f;
        float inv = 1.0f / nrm;
        dnS[tid][0] = dx * inv; dnS[tid][1] = dy * inv; dnS[tid][2] = dz * inv;
        nbS[tid] = nbrow;
    }
    __syncthreads();

    float sdx[16], sdy[16], sdz[16], mx[16];
    for (int p = 0; p < 16; ++p) {
        int pair = p * 256 + tid;
        float ax = dirs[pair], ay = dirs[4096 + pair], az = dirs[8192 + pair];
        float inv = 1.0f / (sqrtf(ax * ax + ay * ay + az * az) + 1e-12f);
        sdx[p] = ax * inv; sdy[p] = ay * inv; sdz[p] = az * inv;
        mx[p] = -INFINITY;
    }
    for (int k = 0; k < 32; ++k) {
        float ex = dnS[k][0], ey = dnS[k][1], ez = dnS[k][2];
        const __hip_bfloat16* fr = fout + (size_t)nbS[k] * 5120 + 1024;
        for (int p = 0; p < 16; ++p) {
            float th = fmaxf(ex * sdx[p] + ey * sdy[p] + ez * sdz[p], 0.0f);
            float s = __bfloat162float(fr[p * 256 + tid]);
            mx[p] = fmaxf(mx[p], th * s);
        }
    }
    for (int q = 0; q < 4; ++q) {
        float val = ((mx[q] + mx[4 + q]) + mx[8 + q]) + mx[12 + q];
        int oo = q * 256 + tid;
        float c = __bfloat162float(fout[(size_t)row * 5120 + oo]);
        G[(size_t)row * 1024 + oo] = c + val;
    }
}

// ---------------------------------------------------------------------------
// Pool: reuses conv idx (pool idx == first 4 of conv idx). Pure gather.
// ---------------------------------------------------------------------------
__global__ void pool_fused_kernel(const int* __restrict__ idx_conv,
                                  const float* __restrict__ verts, int Vp, int Vh, int B,
                                  const float* __restrict__ Fin, int CwIn,
                                  float* __restrict__ Fout, int CwOut, int C,
                                  float* __restrict__ vout)
{
    int wid = (blockIdx.x * blockDim.x + threadIdx.x) >> 6;
    int lane = threadIdx.x & 63;
    int nq = B * Vh;
    if (wid >= nq) return;
    int b = wid / Vh;
    int v = wid - b * Vh;
    int rowc = b * Vp + v;

    int idv = 0;
    if (lane < 4) idv = idx_conv[(size_t)rowc * 32 + lane];
    int i0 = __shfl(idv, 0, 64);
    int i1 = __shfl(idv, 1, 64);
    int i2 = __shfl(idv, 2, 64);
    int i3 = __shfl(idv, 3, 64);

    const float* r0 = Fin + (size_t)(b * Vp + i0) * CwIn;
    const float* r1 = Fin + (size_t)(b * Vp + i1) * CwIn;
    const float* r2p = Fin + (size_t)(b * Vp + i2) * CwIn;
    const float* r3 = Fin + (size_t)(b * Vp + i3) * CwIn;
    for (int c = lane; c < C; c += 64) {
        float m = fmaxf(fmaxf(r0[c], r1[c]), fmaxf(r2p[c], r3[c]));
        Fout[(size_t)wid * CwOut + c] = m;
    }
    if (lane < 3) vout[(size_t)wid * 3 + lane] = verts[(size_t)rowc * 3 + lane];
}

// ---------------------------------------------------------------------------
// Head
// ---------------------------------------------------------------------------
__global__ void gmax_kernel(const float* __restrict__ G, float* __restrict__ gm,
                            int V)
{
    __shared__ float red[4][64];
    int b = blockIdx.x >> 4;
    int c0 = (blockIdx.x & 15) * 64;
    int t = threadIdx.x;
    int c = c0 + (t & 63);
    int vg = t >> 6;
    float m = -INFINITY;
    for (int v = vg * 64; v < (vg + 1) * 64; ++v)
        m = fmaxf(m, G[((size_t)b * V + v) * 1024 + c]);
    red[vg][t & 63] = m;
    __syncthreads();
    if (t < 64) {
        float r = fmaxf(fmaxf(red[0][t], red[1][t]), fmaxf(red[2][t], red[3][t]));
        gm[b * 1024 + c0 + t] = r;
    }
}

__global__ __launch_bounds__(256)
void fc1_kernel(const float* __restrict__ gm, const float* __restrict__ w1,
                const float* __restrict__ b1_,
                const float* __restrict__ bn_g, const float* __restrict__ bn_b,
                const float* __restrict__ bn_m, const float* __restrict__ bn_v,
                float* __restrict__ h)
{
    __shared__ float gs[1024];
    __shared__ float red[8][32];
    int b = blockIdx.y;
    int j0 = blockIdx.x * 32;
    int t = threadIdx.x;
    for (int i = t; i < 1024; i += 256) gs[i] = gm[b * 1024 + i];
    __syncthreads();
    int jj = t & 31, kk = t >> 5;
    int j = j0 + jj;
    const float* wp = w1 + (size_t)(kk * 128) * 256 + j;
    float acc = 0.0f;
#pragma unroll 8
    for (int k = 0; k < 128; ++k)
        acc = fmaf(gs[kk * 128 + k], wp[(size_t)k * 256], acc);
    red[kk][jj] = acc;
    __syncthreads();
    if (t < 32) {
        float s = 0.0f;
#pragma unroll
        for (int q = 0; q < 8; ++q) s += red[q][t];
        int jw = j0 + t;
        s += b1_[jw];
        s = (s - bn_m[jw]) / sqrtf(bn_v[jw] + 1e-5f) * bn_g[jw] + bn_b[jw];
        h[b * 256 + jw] = fmaxf(s, 0.0f);
    }
}

__global__ void fc2_kernel(const float* __restrict__ h, const float* __restrict__ w2,
                           const float* __restrict__ b2_, float* __restrict__ out)
{
    __shared__ float hs[256];
    int b = blockIdx.x;
    int t = threadIdx.x;
    hs[t] = h[b * 256 + t];
    __syncthreads();
    if (t < 40) {
        float acc = 0.0f;
#pragma unroll 8
        for (int k = 0; k < 256; ++k) acc = fmaf(hs[k], w2[(size_t)k * 40 + t], acc);
        out[b * 40 + t] = acc + b2_[t];
    }
}

// ---------------------------------------------------------------------------
static inline int wblocks(int waves) { return (waves + 3) / 4; }
static inline dim3 ggrid(int M, int N) { return dim3(M / 64, (N + 63) / 64); }

extern "C" void kernel_launch(void* const* d_in, const int* in_sizes, int n_in,
                              void* d_out, int out_size, void* d_ws, size_t ws_size,
                              hipStream_t stream)
{
    const int B = 4;
    const float* verts1 = (const float*)d_in[0];
    const float* surf_dirs = (const float*)d_in[1];
    const float* w1 = (const float*)d_in[2];
    const float* b1 = (const float*)d_in[3];
    const float* d1 = (const float*)d_in[4];
    const float* w3 = (const float*)d_in[5];
    const float* b3 = (const float*)d_in[6];
    const float* d3 = (const float*)d_in[7];
    const float* w4 = (const float*)d_in[8];
    const float* b4 = (const float*)d_in[9];
    const float* d4 = (const float*)d_in[10];
    const float* w6 = (const float*)d_in[11];
    const float* b6 = (const float*)d_in[12];
    const float* d6 = (const float*)d_in[13];
    const float* w7 = (const float*)d_in[14];
    const float* b7 = (const float*)d_in[15];
    const float* d7 = (const float*)d_in[16];
    const float* w8 = (const float*)d_in[17];
    const float* b8 = (const float*)d_in[18];
    const float* d8 = (const float*)d_in[19];
    const float* w9 = (const float*)d_in[20];
    const float* b9 = (const float*)d_in[21];
    const float* d9 = (const float*)d_in[22];
    const float* w10 = (const float*)d_in[23];
    const float* b10 = (const float*)d_in[24];
    const float* d10 = (const float*)d_in[25];
    const float* w11 = (const float*)d_in[26];
    const float* b11 = (const float*)d_in[27];
    const float* d11 = (const float*)d_in[28];
    const float* fc1_w = (const float*)d_in[29];
    const float* fc1_b = (const float*)d_in[30];
    const float* bn_g = (const float*)d_in[31];
    const float* bn_b = (const float*)d_in[32];
    const float* bn_m = (const float*)d_in[33];
    const float* bn_v = (const float*)d_in[34];
    const float* fc2_w = (const float*)d_in[35];
    const float* fc2_b = (const float*)d_in[36];
    (void)in_sizes; (void)n_in; (void)out_size; (void)ws_size;

    float* ws = (float*)d_ws;
    size_t off = 0;
    auto alloc = [&](size_t n) { float* p = ws + off; off += n; return p; };
    float* fout = alloc(4 * 256 * 5120);
    int* idx = (int*)alloc(4 * 4096 * 32);
    float* F1 = alloc(4 * 4096 * 64);
    float* L2 = alloc(4 * 2048 * 128);
    float* L3 = alloc(4 * 1024 * 192);
    float* L4 = alloc(4 * 512 * 256);
    float* L5 = alloc(4 * 256 * 288);
    float* G = alloc(4 * 256 * 1024);
    float* v2 = alloc(4 * 2048 * 3);
    float* v3 = alloc(4 * 1024 * 3);
    float* v4 = alloc(4 * 512 * 3);
    float* v5 = alloc(4 * 256 * 3);
    float* gm = alloc(4 * 1024);
    float* hh = alloc(4 * 256);

    // bf16 staging for conv11 MFMA aliased into G (G is written only later
    // by conv_agg_big, after the GEMM has consumed these).
    unsigned short* Abf = (unsigned short*)G;           // 1024*288 bf16
    unsigned short* WTbf = Abf + 1024 * 288;            // 5120*288 bf16

    // ---- Level 1 (V=4096, r=0.2) ----
    qb_surface_kernel<<<wblocks(B * 4096), 256, 0, stream>>>(verts1, 4096, B, 0.04f, surf_dirs, F1, 64, idx);
    gemm_tiled_kernel<float><<<ggrid(B * 4096, 160), 256, 0, stream>>>(F1, 64, 32, w1, b1, 160, fout);
    conv_agg32_kernel<<<B * 4096 / 4, 256, 0, stream>>>(idx, verts1, fout, d1, F1, 64, 32, 4096, 1);
    pool_fused_kernel<<<wblocks(B * 2048), 256, 0, stream>>>(idx, verts1, 4096, 2048, B, F1, 64, L2, 128, 64, v2);

    // ---- Level 2 (V=2048, r=0.4) ----
    qb_kernel<<<wblocks(B * 2048), 256, 0, stream>>>(v2, 2048, 2048, B, 0.16f, 32, idx);
    gemm_tiled_kernel<float><<<ggrid(B * 2048, 160), 256, 0, stream>>>(L2, 128, 64, w3, b3, 160, fout);
    conv_agg32_kernel<<<B * 2048 / 4, 256, 0, stream>>>(idx, v2, fout, d3, L2, 128, 64, 2048, 1);
    gemm_tiled_kernel<float><<<ggrid(B * 2048, 160), 256, 0, stream>>>(L2, 128, 96, w4, b4, 160, fout);
    conv_agg32_kernel<<<B * 2048 / 4, 256, 0, stream>>>(idx, v2, fout, d4, L2, 128, 96, 2048, 1);
    pool_fused_kernel<<<wblocks(B * 1024), 256, 0, stream>>>(idx, v2, 2048, 1024, B, L2, 128, L3, 192, 128, v3);

    // ---- Level 3 (V=1024, r=0.6) ----
    qb_kernel<<<wblocks(B * 1024), 256, 0, stream>>>(v3, 1024, 1024, B, 0.36f, 32, idx);
    gemm_tiled_kernel<float><<<ggrid(B * 1024, 160), 256, 0, stream>>>(L3, 192, 128, w6, b6, 160, fout);
    conv_agg32_kernel<<<B * 1024 / 4, 256, 0, stream>>>(idx, v3, fout, d6, L3, 192, 128, 1024, 1);
    gemm_tiled_kernel<float><<<ggrid(B * 1024, 160), 256, 0, stream>>>(L3, 192, 160, w7, b7, 160, fout);
    conv_agg32_kernel<<<B * 1024 / 4, 256, 0, stream>>>(idx, v3, fout, d7, L3, 192, 160, 1024, 1);
    pool_fused_kernel<<<wblocks(B * 512), 256, 0, stream>>>(idx, v3, 1024, 512, B, L3, 192, L4, 256, 192, v4);

    // ---- Level 4 (V=512, r=0.8) ----
    qb_kernel<<<wblocks(B * 512), 256, 0, stream>>>(v4, 512, 512, B, 0.64f, 32, idx);
    gemm_tiled_kernel<float><<<ggrid(B * 512, 160), 256, 0, stream>>>(L4, 256, 192, w8, b8, 160, fout);
    conv_agg32_kernel<<<B * 512 / 4, 256, 0, stream>>>(idx, v4, fout, d8, L4, 256, 192, 512, 1);
    gemm_tiled_kernel<float><<<ggrid(B * 512, 160), 256, 0, stream>>>(L4, 256, 224, w9, b9, 160, fout);
    conv_agg32_kernel<<<B * 512 / 4, 256, 0, stream>>>(idx, v4, fout, d9, L4, 256, 224, 512, 1);
    pool_fused_kernel<<<wblocks(B * 256), 256, 0, stream>>>(idx, v4, 512, 256, B, L4, 256, L5, 288, 256, v5);

    // ---- Level 5 (V=256, r=1.0) ----
    qb_kernel<<<wblocks(B * 256), 256, 0, stream>>>(v5, 256, 256, B, 1.0f, 32, idx);
    castT_bf16_kernel<<<(5120 * 36 + 255) / 256, 256, 0, stream>>>(w11, WTbf);
    gemm_tiled_kernel<float><<<ggrid(B * 256, 160), 256, 0, stream>>>(L5, 288, 256, w10, b10, 160, fout);
    conv_agg32_kernel<<<B * 256 / 4, 256, 0, stream>>>(idx, v5, fout, d10, L5, 288, 256, 256, 1);
    cast_bf16_kernel<<<(36864 + 255) / 256, 256, 0, stream>>>(L5, Abf, 36864);
    __hip_bfloat16* fout_bf = (__hip_bfloat16*)fout;
    gemm_mfma_conv11<<<dim3(8, 40), 256, 0, stream>>>(Abf, WTbf, b11, fout_bf);
    conv_agg_big_kernel<<<B * 256, 256, 0, stream>>>(idx, v5, fout_bf, d11, G, 256, B);

    // ---- Head ----
    gmax_kernel<<<64, 256, 0, stream>>>(G, gm, 256);
    fc1_kernel<<<dim3(8, B), 256, 0, stream>>>(gm, fc1_w, fc1_b, bn_g, bn_b, bn_m, bn_v, hh);
    fc2_kernel<<<B, 256, 0, stream>>>(hh, fc2_w, fc2_b, (float*)d_out);
}